// Round 7
// baseline (896.710 us; speedup 1.0000x reference)
//
#include <hip/hip_runtime.h>
#include <hip/hip_bf16.h>

#define NN 50000
#define EE 800000
#define ETOT 850000
#define BB 512
#define NBLK 196  // ceil(NN/256)

typedef __hip_bfloat16 bf16;

__device__ __forceinline__ float b2f(bf16 v) { return __bfloat162float(v); }

// ---------------- zeroing ----------------
__global__ void k_zeroi(int* __restrict__ p, int n) {
    int i = blockIdx.x * blockDim.x + threadIdx.x;
    if (i < n) p[i] = 0;
}
__global__ void k_zerof(float* __restrict__ p, int n) {
    int i = blockIdx.x * blockDim.x + threadIdx.x;
    if (i < n) p[i] = 0.f;
}

// ---------------- CSR build ----------------
__global__ void k_count(const int* __restrict__ dstArr, int* __restrict__ deg) {
    int e = blockIdx.x * blockDim.x + threadIdx.x;
    if (e >= ETOT) return;
    int d = (e < EE) ? dstArr[e] : (e - EE);
    d = min(max(d, 0), NN - 1);
    atomicAdd(&deg[d], 1);
}

__global__ void k_scan1(const int* __restrict__ deg, int* __restrict__ offs,
                        int* __restrict__ cur, int* __restrict__ bsum) {
    __shared__ int s[256];
    int t = threadIdx.x;
    int i = blockIdx.x * 256 + t;
    int v = (i < NN) ? deg[i] : 0;
    s[t] = v;
    __syncthreads();
    for (int o = 1; o < 256; o <<= 1) {
        int tv = (t >= o) ? s[t - o] : 0;
        __syncthreads();
        s[t] += tv;
        __syncthreads();
    }
    int excl = s[t] - v;
    if (i < NN) { offs[i] = excl; cur[i] = excl; }
    if (t == 255) bsum[blockIdx.x] = s[255];
}

__global__ void k_scan2(const int* __restrict__ bsum, int* __restrict__ boff,
                        int* __restrict__ offs) {
    __shared__ int s[256];
    int t = threadIdx.x;
    int v = (t < NBLK) ? bsum[t] : 0;
    s[t] = v;
    __syncthreads();
    for (int o = 1; o < 256; o <<= 1) {
        int tv = (t >= o) ? s[t - o] : 0;
        __syncthreads();
        s[t] += tv;
        __syncthreads();
    }
    if (t < NBLK) boff[t] = s[t] - v;
    if (t == 0) offs[NN] = ETOT;
}

__global__ void k_scan3(const int* __restrict__ boff, int* __restrict__ offs,
                        int* __restrict__ cur) {
    int i = blockIdx.x * 256 + threadIdx.x;
    if (i < NN) {
        int b = boff[blockIdx.x];
        offs[i] += b;
        cur[i] += b;
    }
}

__global__ void k_scatter(const int* __restrict__ dstArr, int* __restrict__ cur,
                          int* __restrict__ eid) {
    int e = blockIdx.x * blockDim.x + threadIdx.x;
    if (e >= ETOT) return;
    int d = (e < EE) ? dstArr[e] : (e - EE);
    d = min(max(d, 0), NN - 1);
    int p = atomicAdd(&cur[d], 1);
    if (p >= 0 && p < ETOT) eid[p] = e;
}

// ---------------- Layer 1 GEMM + alpha reductions ----------------
// one node per block, 256 threads; col t of h1; head h = t>>6 (one wave per head)
__global__ void k_gemm1(const float* __restrict__ x, const float* __restrict__ W1,
                        const float* __restrict__ aw_s, const float* __restrict__ aw_d,
                        bf16* __restrict__ h1, float* __restrict__ as1,
                        float* __restrict__ ad1) {
    int n = blockIdx.x;
    int t = threadIdx.x;
    __shared__ float xs[128];
    if (t < 128) xs[t] = x[n * 128 + t];
    __syncthreads();
    float acc = 0.f;
#pragma unroll 8
    for (int k = 0; k < 128; k++) acc += xs[k] * W1[k * 256 + t];
    h1[n * 256 + t] = __float2bfloat16(acc);
    float ps = acc * aw_s[t];   // a_src1 is (4,64) flat: index == t
    float pd = acc * aw_d[t];
    for (int o = 32; o > 0; o >>= 1) {
        ps += __shfl_down(ps, o);
        pd += __shfl_down(pd, o);
    }
    if ((t & 63) == 0) {
        int h = t >> 6;
        as1[n * 4 + h] = ps;
        ad1[n * 4 + h] = pd;
    }
}

// ---------------- Layer 1 aggregation (online softmax over incoming edges) ----------------
__global__ void k_agg1(const int* __restrict__ srcArr, const int* __restrict__ offs,
                       const int* __restrict__ eid, const bf16* __restrict__ h1,
                       const float* __restrict__ as1, const float* __restrict__ ad1,
                       const float* __restrict__ b1, bf16* __restrict__ x2) {
    int n = blockIdx.x;
    int t = threadIdx.x;
    int h = t >> 6;
    int beg = offs[n], end = offs[n + 1];
    beg = min(max(beg, 0), ETOT);
    end = min(max(end, beg), ETOT);
    float adh = ad1[n * 4 + h];
    float m = -1e30f, ssum = 0.f, acc = 0.f;
    __shared__ int ls[64];
    for (int cb = beg; cb < end; cb += 64) {
        int cnt = min(64, end - cb);
        __syncthreads();
        if (t < cnt) {
            int e = eid[cb + t];
            e = min(max(e, 0), ETOT - 1);
            int s = (e < EE) ? srcArr[e] : (e - EE);
            ls[t] = min(max(s, 0), NN - 1);
        }
        __syncthreads();
        for (int j = 0; j < cnt; j++) {
            int s = ls[j];
            float ev = as1[s * 4 + h] + adh;
            ev = ev > 0.f ? ev : 0.2f * ev;       // leaky_relu(0.2)
            float mn = fmaxf(m, ev);
            float fo = __expf(m - mn);
            float wgt = __expf(ev - mn);
            ssum = ssum * fo + wgt;
            acc = acc * fo + wgt * b2f(h1[s * 256 + t]);
            m = mn;
        }
    }
    float r = acc / fmaxf(ssum, 1e-30f) + b1[t];
    x2[n * 256 + t] = __float2bfloat16(r > 0.f ? r : (__expf(r) - 1.f));  // ELU
}

// ---------------- Layer 2 GEMM + alpha reductions (H=1, Fo=128) ----------------
__global__ void k_gemm2(const bf16* __restrict__ x2, const float* __restrict__ W2,
                        const float* __restrict__ aw_s, const float* __restrict__ aw_d,
                        bf16* __restrict__ h2, float* __restrict__ as2,
                        float* __restrict__ ad2) {
    int n = blockIdx.x;
    int t = threadIdx.x;
    __shared__ float xs[256];
    xs[t] = b2f(x2[n * 256 + t]);
    xs[t + 128] = b2f(x2[n * 256 + 128 + t]);
    __syncthreads();
    float acc = 0.f;
#pragma unroll 8
    for (int k = 0; k < 256; k++) acc += xs[k] * W2[k * 128 + t];
    h2[n * 128 + t] = __float2bfloat16(acc);
    float ps = acc * aw_s[t];
    float pd = acc * aw_d[t];
    for (int o = 32; o > 0; o >>= 1) {
        ps += __shfl_down(ps, o);
        pd += __shfl_down(pd, o);
    }
    __shared__ float red[4];
    int wv = t >> 6, ln = t & 63;
    if (ln == 0) { red[wv * 2] = ps; red[wv * 2 + 1] = pd; }
    __syncthreads();
    if (t == 0) {
        as2[n] = red[0] + red[2];
        ad2[n] = red[1] + red[3];
    }
}

// ---------------- Layer 2 aggregation ----------------
__global__ void k_agg2(const int* __restrict__ srcArr, const int* __restrict__ offs,
                       const int* __restrict__ eid, const bf16* __restrict__ h2,
                       const float* __restrict__ as2, const float* __restrict__ ad2,
                       const float* __restrict__ b2, float* __restrict__ hf) {
    int n = blockIdx.x;
    int t = threadIdx.x;
    int beg = offs[n], end = offs[n + 1];
    beg = min(max(beg, 0), ETOT);
    end = min(max(end, beg), ETOT);
    float adn = ad2[n];
    float m = -1e30f, ssum = 0.f, acc = 0.f;
    __shared__ int ls[64];
    for (int cb = beg; cb < end; cb += 64) {
        int cnt = min(64, end - cb);
        __syncthreads();
        if (t < cnt) {
            int e = eid[cb + t];
            e = min(max(e, 0), ETOT - 1);
            int s = (e < EE) ? srcArr[e] : (e - EE);
            ls[t] = min(max(s, 0), NN - 1);
        }
        __syncthreads();
        for (int j = 0; j < cnt; j++) {
            int s = ls[j];
            float ev = as2[s] + adn;
            ev = ev > 0.f ? ev : 0.2f * ev;
            float mn = fmaxf(m, ev);
            float fo = __expf(m - mn);
            float wgt = __expf(ev - mn);
            ssum = ssum * fo + wgt;
            acc = acc * fo + wgt * b2f(h2[s * 128 + t]);
            m = mn;
        }
    }
    float r = acc / fmaxf(ssum, 1e-30f) + b2[t];
    hf[n * 128 + t] = r > 0.f ? r : (__expf(r) - 1.f);  // ELU
}

// ---------------- global mean pool (atomics) ----------------
__global__ void k_pool(const float* __restrict__ hf, const int* __restrict__ batch,
                       float* __restrict__ pooled, int* __restrict__ cnt) {
    int n = blockIdx.x;
    int t = threadIdx.x;
    int b = batch[n];
    b = min(max(b, 0), BB - 1);
    atomicAdd(&pooled[b * 128 + t], hf[n * 128 + t]);
    if (t == 0) atomicAdd(&cnt[b], 1);
}

// ---------------- final linear + sigmoid (FLOAT32 output) ----------------
__global__ void k_final(const float* __restrict__ pooled, const int* __restrict__ cnt,
                        const float* __restrict__ Wl, const float* __restrict__ bl,
                        float* __restrict__ out) {
    int b = blockIdx.x * blockDim.x + threadIdx.x;
    if (b >= BB) return;
    float acc = 0.f;
    for (int k = 0; k < 128; k++) acc += pooled[b * 128 + k] * Wl[k];
    int c = cnt[b];
    float cf = (float)(c > 0 ? c : 1);
    float g = acc / cf + bl[0];
    out[b] = 1.f / (1.f + __expf(-g));
}

extern "C" void kernel_launch(void* const* d_in, const int* in_sizes, int n_in,
                              void* d_out, int out_size, void* d_ws, size_t ws_size,
                              hipStream_t stream) {
    // reference dtypes: float32 everywhere; ints int32; OUTPUT float32
    const float* x = (const float*)d_in[0];
    const int* ei = (const int*)d_in[1];
    const int* batch = (const int*)d_in[2];
    const float* W1 = (const float*)d_in[3];
    const float* aw_s1 = (const float*)d_in[4];
    const float* aw_d1 = (const float*)d_in[5];
    const float* b1 = (const float*)d_in[6];
    const float* W2 = (const float*)d_in[7];
    const float* aw_s2 = (const float*)d_in[8];
    const float* aw_d2 = (const float*)d_in[9];
    const float* b2 = (const float*)d_in[10];
    const float* Wl = (const float*)d_in[11];
    const float* bl = (const float*)d_in[12];
    const int* srcArr = ei;        // edge_index[0]
    const int* dstArr = ei + EE;   // edge_index[1]

    char* w = (char*)d_ws;
    size_t off = 0;
    auto alloc = [&](size_t bytes) -> void* {
        void* p = (void*)(w + off);
        off = (off + bytes + 255) & ~(size_t)255;
        return p;
    };
    // ~57 MB total (footprint proven fault-free in earlier rounds)
    bf16* bufA = (bf16*)alloc((size_t)NN * 256 * 2);  // h1 [N,256] bf16; later h2 [N,128] bf16
    char* bufB = (char*)alloc((size_t)NN * 256 * 2);  // x2 [N,256] bf16; later hf [N,128] f32
    float* as1 = (float*)alloc((size_t)NN * 4 * 4);
    float* ad1 = (float*)alloc((size_t)NN * 4 * 4);
    float* as2 = (float*)alloc((size_t)NN * 4);
    float* ad2 = (float*)alloc((size_t)NN * 4);
    int* deg = (int*)alloc((size_t)NN * 4);
    int* offs = (int*)alloc((size_t)(NN + 1) * 4);
    int* cur = (int*)alloc((size_t)NN * 4);
    int* eid = (int*)alloc((size_t)ETOT * 4);
    int* bsum = (int*)alloc((size_t)NBLK * 4);
    int* boff = (int*)alloc((size_t)NBLK * 4);
    float* pooled = (float*)alloc((size_t)BB * 128 * 4);
    int* cnt = (int*)alloc((size_t)BB * 4);
    (void)ws_size;

    // zero scratch
    k_zeroi<<<NBLK, 256, 0, stream>>>(deg, NN);
    k_zerof<<<(BB * 128 + 255) / 256, 256, 0, stream>>>(pooled, BB * 128);
    k_zeroi<<<(BB + 255) / 256, 256, 0, stream>>>(cnt, BB);

    // CSR over dst (self-loops appended: edge id e>=EE has src=dst=e-EE)
    k_count<<<(ETOT + 255) / 256, 256, 0, stream>>>(dstArr, deg);
    k_scan1<<<NBLK, 256, 0, stream>>>(deg, offs, cur, bsum);
    k_scan2<<<1, 256, 0, stream>>>(bsum, boff, offs);
    k_scan3<<<NBLK, 256, 0, stream>>>(boff, offs, cur);
    k_scatter<<<(ETOT + 255) / 256, 256, 0, stream>>>(dstArr, cur, eid);

    bf16* h1 = bufA;
    bf16* x2 = (bf16*)bufB;
    k_gemm1<<<NN, 256, 0, stream>>>(x, W1, aw_s1, aw_d1, h1, as1, ad1);
    k_agg1<<<NN, 256, 0, stream>>>(srcArr, offs, eid, h1, as1, ad1, b1, x2);

    bf16* h2 = bufA;  // h1 dead after agg1
    k_gemm2<<<NN, 128, 0, stream>>>(x2, W2, aw_s2, aw_d2, h2, as2, ad2);

    float* hf = (float*)bufB;  // x2 dead after gemm2; [N,128] f32 fits exactly
    k_agg2<<<NN, 128, 0, stream>>>(srcArr, offs, eid, h2, as2, ad2, b2, hf);

    k_pool<<<NN, 128, 0, stream>>>(hf, batch, pooled, cnt);
    k_final<<<2, 256, 0, stream>>>(pooled, cnt, Wl, bl, (float*)d_out);
}

// Round 8
// 648.234 us; speedup vs baseline: 1.3833x; 1.3833x over previous
//
#include <hip/hip_runtime.h>
#include <hip/hip_bf16.h>

#define NN 50000
#define EE 800000
#define ETOT 850000
#define BB 512
#define NBLK 196   // ceil(NN/256)
#define TM 8       // nodes per GEMM block (50000 = 6250*8)

typedef __hip_bfloat16 bf16;

__device__ __forceinline__ float b2f(bf16 v) { return __bfloat162float(v); }
__device__ __forceinline__ float us2f(unsigned short u) {
    return __uint_as_float(((unsigned int)u) << 16);
}

// ---------------- zeroing ----------------
__global__ void k_zeroi(int* __restrict__ p, int n) {
    int i = blockIdx.x * blockDim.x + threadIdx.x;
    if (i < n) p[i] = 0;
}
__global__ void k_zerof(float* __restrict__ p, int n) {
    int i = blockIdx.x * blockDim.x + threadIdx.x;
    if (i < n) p[i] = 0.f;
}

// ---------------- CSR build ----------------
__global__ void k_count(const int* __restrict__ dstArr, int* __restrict__ deg) {
    int e = blockIdx.x * blockDim.x + threadIdx.x;
    if (e >= ETOT) return;
    int d = (e < EE) ? dstArr[e] : (e - EE);
    d = min(max(d, 0), NN - 1);
    atomicAdd(&deg[d], 1);
}

__global__ void k_scan1(const int* __restrict__ deg, int* __restrict__ offs,
                        int* __restrict__ cur, int* __restrict__ bsum) {
    __shared__ int s[256];
    int t = threadIdx.x;
    int i = blockIdx.x * 256 + t;
    int v = (i < NN) ? deg[i] : 0;
    s[t] = v;
    __syncthreads();
    for (int o = 1; o < 256; o <<= 1) {
        int tv = (t >= o) ? s[t - o] : 0;
        __syncthreads();
        s[t] += tv;
        __syncthreads();
    }
    int excl = s[t] - v;
    if (i < NN) { offs[i] = excl; cur[i] = excl; }
    if (t == 255) bsum[blockIdx.x] = s[255];
}

__global__ void k_scan2(const int* __restrict__ bsum, int* __restrict__ boff,
                        int* __restrict__ offs) {
    __shared__ int s[256];
    int t = threadIdx.x;
    int v = (t < NBLK) ? bsum[t] : 0;
    s[t] = v;
    __syncthreads();
    for (int o = 1; o < 256; o <<= 1) {
        int tv = (t >= o) ? s[t - o] : 0;
        __syncthreads();
        s[t] += tv;
        __syncthreads();
    }
    if (t < NBLK) boff[t] = s[t] - v;
    if (t == 0) offs[NN] = ETOT;
}

__global__ void k_scan3(const int* __restrict__ boff, int* __restrict__ offs,
                        int* __restrict__ cur) {
    int i = blockIdx.x * 256 + threadIdx.x;
    if (i < NN) {
        int b = boff[blockIdx.x];
        offs[i] += b;
        cur[i] += b;
    }
}

__global__ void k_scatter(const int* __restrict__ dstArr, int* __restrict__ cur,
                          int* __restrict__ eid) {
    int e = blockIdx.x * blockDim.x + threadIdx.x;
    if (e >= ETOT) return;
    int d = (e < EE) ? dstArr[e] : (e - EE);
    d = min(max(d, 0), NN - 1);
    int p = atomicAdd(&cur[d], 1);
    if (p >= 0 && p < ETOT) eid[p] = e;
}

// ---------------- Layer 1 GEMM (register-tiled, TM=8) ----------------
// grid 6250, block 256: thread t = output col; 8 nodes per block.
__global__ void k_gemm1(const float* __restrict__ x, const float* __restrict__ W1,
                        const float* __restrict__ aw_s, const float* __restrict__ aw_d,
                        bf16* __restrict__ h1, float* __restrict__ as1,
                        float* __restrict__ ad1) {
    int n0 = blockIdx.x * TM;
    int t = threadIdx.x;
    __shared__ float xs[TM * 128];   // 4 KB
    {
        int n = t >> 5;              // 0..7
        int c4 = t & 31;             // 0..31 -> k = c4*4
        float4 v = *(const float4*)&x[(size_t)(n0 + n) * 128 + c4 * 4];
        *(float4*)&xs[n * 128 + c4 * 4] = v;
    }
    __syncthreads();
    float acc[TM];
#pragma unroll
    for (int n = 0; n < TM; n++) acc[n] = 0.f;
    for (int kc = 0; kc < 32; kc++) {
        float w0 = W1[(kc * 4 + 0) * 256 + t];
        float w1 = W1[(kc * 4 + 1) * 256 + t];
        float w2 = W1[(kc * 4 + 2) * 256 + t];
        float w3 = W1[(kc * 4 + 3) * 256 + t];
#pragma unroll
        for (int n = 0; n < TM; n++) {
            float4 xv = *(const float4*)&xs[n * 128 + kc * 4];
            acc[n] += xv.x * w0;
            acc[n] += xv.y * w1;
            acc[n] += xv.z * w2;
            acc[n] += xv.w * w3;
        }
    }
    float s_t = aw_s[t], d_t = aw_d[t];
    int h = t >> 6, ln = t & 63;
#pragma unroll
    for (int n = 0; n < TM; n++) {
        h1[(size_t)(n0 + n) * 256 + t] = __float2bfloat16(acc[n]);
        float ps = acc[n] * s_t;
        float pd = acc[n] * d_t;
        for (int o = 32; o > 0; o >>= 1) {
            ps += __shfl_down(ps, o);
            pd += __shfl_down(pd, o);
        }
        if (ln == 0) {
            as1[(n0 + n) * 4 + h] = ps;
            ad1[(n0 + n) * 4 + h] = pd;
        }
    }
}

// ---------------- Layer 1 aggregation (online softmax) ----------------
__global__ void k_agg1(const int* __restrict__ srcArr, const int* __restrict__ offs,
                       const int* __restrict__ eid, const bf16* __restrict__ h1,
                       const float* __restrict__ as1, const float* __restrict__ ad1,
                       const float* __restrict__ b1, bf16* __restrict__ x2) {
    int n = blockIdx.x;
    int t = threadIdx.x;
    int h = t >> 6;
    int beg = offs[n], end = offs[n + 1];
    beg = min(max(beg, 0), ETOT);
    end = min(max(end, beg), ETOT);
    float adh = ad1[n * 4 + h];
    float m = -1e30f, ssum = 0.f, acc = 0.f;
    __shared__ int ls[64];
    for (int cb = beg; cb < end; cb += 64) {
        int cnt = min(64, end - cb);
        __syncthreads();
        if (t < cnt) {
            int e = eid[cb + t];
            e = min(max(e, 0), ETOT - 1);
            int s = (e < EE) ? srcArr[e] : (e - EE);
            ls[t] = min(max(s, 0), NN - 1);
        }
        __syncthreads();
        for (int j = 0; j < cnt; j++) {
            int s = ls[j];
            float ev = as1[s * 4 + h] + adh;
            ev = ev > 0.f ? ev : 0.2f * ev;
            float mn = fmaxf(m, ev);
            float fo = __expf(m - mn);
            float wgt = __expf(ev - mn);
            ssum = ssum * fo + wgt;
            acc = acc * fo + wgt * b2f(h1[s * 256 + t]);
            m = mn;
        }
    }
    float r = acc / fmaxf(ssum, 1e-30f) + b1[t];
    x2[n * 256 + t] = __float2bfloat16(r > 0.f ? r : (__expf(r) - 1.f));  // ELU
}

// ---------------- Layer 2 GEMM (register-tiled, TM=8, bf16 input) ----------------
// grid 6250, block 128
__global__ void k_gemm2(const bf16* __restrict__ x2, const float* __restrict__ W2,
                        const float* __restrict__ aw_s, const float* __restrict__ aw_d,
                        bf16* __restrict__ h2, float* __restrict__ as2,
                        float* __restrict__ ad2) {
    int n0 = blockIdx.x * TM;
    int t = threadIdx.x;
    __shared__ float xs[TM * 256];   // 8 KB
    {
        int n = t >> 4;              // 0..7
        int c = t & 15;              // 0..15 -> k base c*16
        const unsigned short* xr =
            (const unsigned short*)x2 + (size_t)(n0 + n) * 256 + c * 16;
#pragma unroll
        for (int k4 = 0; k4 < 4; k4++) {
            ushort4 u = *(const ushort4*)(xr + k4 * 4);
            float4 v;
            v.x = us2f(u.x); v.y = us2f(u.y); v.z = us2f(u.z); v.w = us2f(u.w);
            *(float4*)&xs[n * 256 + c * 16 + k4 * 4] = v;
        }
    }
    __syncthreads();
    float acc[TM];
#pragma unroll
    for (int n = 0; n < TM; n++) acc[n] = 0.f;
    for (int kc = 0; kc < 64; kc++) {
        float w0 = W2[(kc * 4 + 0) * 128 + t];
        float w1 = W2[(kc * 4 + 1) * 128 + t];
        float w2 = W2[(kc * 4 + 2) * 128 + t];
        float w3 = W2[(kc * 4 + 3) * 128 + t];
#pragma unroll
        for (int n = 0; n < TM; n++) {
            float4 xv = *(const float4*)&xs[n * 256 + kc * 4];
            acc[n] += xv.x * w0;
            acc[n] += xv.y * w1;
            acc[n] += xv.z * w2;
            acc[n] += xv.w * w3;
        }
    }
    __shared__ float redS[TM][2];
    __shared__ float redD[TM][2];
    float s_t = aw_s[t], d_t = aw_d[t];
    int wv = t >> 6, ln = t & 63;
#pragma unroll
    for (int n = 0; n < TM; n++) {
        h2[(size_t)(n0 + n) * 128 + t] = __float2bfloat16(acc[n]);
        float ps = acc[n] * s_t;
        float pd = acc[n] * d_t;
        for (int o = 32; o > 0; o >>= 1) {
            ps += __shfl_down(ps, o);
            pd += __shfl_down(pd, o);
        }
        if (ln == 0) { redS[n][wv] = ps; redD[n][wv] = pd; }
    }
    __syncthreads();
    if (t < TM) {
        as2[n0 + t] = redS[t][0] + redS[t][1];
        ad2[n0 + t] = redD[t][0] + redD[t][1];
    }
}

// ---------------- Layer 2 aggregation ----------------
__global__ void k_agg2(const int* __restrict__ srcArr, const int* __restrict__ offs,
                       const int* __restrict__ eid, const bf16* __restrict__ h2,
                       const float* __restrict__ as2, const float* __restrict__ ad2,
                       const float* __restrict__ b2, float* __restrict__ hf) {
    int n = blockIdx.x;
    int t = threadIdx.x;
    int beg = offs[n], end = offs[n + 1];
    beg = min(max(beg, 0), ETOT);
    end = min(max(end, beg), ETOT);
    float adn = ad2[n];
    float m = -1e30f, ssum = 0.f, acc = 0.f;
    __shared__ int ls[64];
    for (int cb = beg; cb < end; cb += 64) {
        int cnt = min(64, end - cb);
        __syncthreads();
        if (t < cnt) {
            int e = eid[cb + t];
            e = min(max(e, 0), ETOT - 1);
            int s = (e < EE) ? srcArr[e] : (e - EE);
            ls[t] = min(max(s, 0), NN - 1);
        }
        __syncthreads();
        for (int j = 0; j < cnt; j++) {
            int s = ls[j];
            float ev = as2[s] + adn;
            ev = ev > 0.f ? ev : 0.2f * ev;
            float mn = fmaxf(m, ev);
            float fo = __expf(m - mn);
            float wgt = __expf(ev - mn);
            ssum = ssum * fo + wgt;
            acc = acc * fo + wgt * b2f(h2[s * 128 + t]);
            m = mn;
        }
    }
    float r = acc / fmaxf(ssum, 1e-30f) + b2[t];
    hf[n * 128 + t] = r > 0.f ? r : (__expf(r) - 1.f);  // ELU
}

// ---------------- global mean pool (atomics) ----------------
__global__ void k_pool(const float* __restrict__ hf, const int* __restrict__ batch,
                       float* __restrict__ pooled, int* __restrict__ cnt) {
    int n = blockIdx.x;
    int t = threadIdx.x;
    int b = batch[n];
    b = min(max(b, 0), BB - 1);
    atomicAdd(&pooled[b * 128 + t], hf[n * 128 + t]);
    if (t == 0) atomicAdd(&cnt[b], 1);
}

// ---------------- final linear + sigmoid (f32 output) ----------------
__global__ void k_final(const float* __restrict__ pooled, const int* __restrict__ cnt,
                        const float* __restrict__ Wl, const float* __restrict__ bl,
                        float* __restrict__ out) {
    int b = blockIdx.x * blockDim.x + threadIdx.x;
    if (b >= BB) return;
    float acc = 0.f;
    for (int k = 0; k < 128; k++) acc += pooled[b * 128 + k] * Wl[k];
    int c = cnt[b];
    float cf = (float)(c > 0 ? c : 1);
    float g = acc / cf + bl[0];
    out[b] = 1.f / (1.f + __expf(-g));
}

extern "C" void kernel_launch(void* const* d_in, const int* in_sizes, int n_in,
                              void* d_out, int out_size, void* d_ws, size_t ws_size,
                              hipStream_t stream) {
    const float* x = (const float*)d_in[0];
    const int* ei = (const int*)d_in[1];
    const int* batch = (const int*)d_in[2];
    const float* W1 = (const float*)d_in[3];
    const float* aw_s1 = (const float*)d_in[4];
    const float* aw_d1 = (const float*)d_in[5];
    const float* b1 = (const float*)d_in[6];
    const float* W2 = (const float*)d_in[7];
    const float* aw_s2 = (const float*)d_in[8];
    const float* aw_d2 = (const float*)d_in[9];
    const float* b2 = (const float*)d_in[10];
    const float* Wl = (const float*)d_in[11];
    const float* bl = (const float*)d_in[12];
    const int* srcArr = ei;        // edge_index[0]
    const int* dstArr = ei + EE;   // edge_index[1]

    char* w = (char*)d_ws;
    size_t off = 0;
    auto alloc = [&](size_t bytes) -> void* {
        void* p = (void*)(w + off);
        off = (off + bytes + 255) & ~(size_t)255;
        return p;
    };
    bf16* bufA = (bf16*)alloc((size_t)NN * 256 * 2);  // h1 [N,256] bf16; later h2 [N,128] bf16
    char* bufB = (char*)alloc((size_t)NN * 256 * 2);  // x2 [N,256] bf16; later hf [N,128] f32
    float* as1 = (float*)alloc((size_t)NN * 4 * 4);
    float* ad1 = (float*)alloc((size_t)NN * 4 * 4);
    float* as2 = (float*)alloc((size_t)NN * 4);
    float* ad2 = (float*)alloc((size_t)NN * 4);
    int* deg = (int*)alloc((size_t)NN * 4);
    int* offs = (int*)alloc((size_t)(NN + 1) * 4);
    int* cur = (int*)alloc((size_t)NN * 4);
    int* eid = (int*)alloc((size_t)ETOT * 4);
    int* bsum = (int*)alloc((size_t)NBLK * 4);
    int* boff = (int*)alloc((size_t)NBLK * 4);
    float* pooled = (float*)alloc((size_t)BB * 128 * 4);
    int* cnt = (int*)alloc((size_t)BB * 4);
    (void)ws_size;

    k_zeroi<<<NBLK, 256, 0, stream>>>(deg, NN);
    k_zerof<<<(BB * 128 + 255) / 256, 256, 0, stream>>>(pooled, BB * 128);
    k_zeroi<<<(BB + 255) / 256, 256, 0, stream>>>(cnt, BB);

    k_count<<<(ETOT + 255) / 256, 256, 0, stream>>>(dstArr, deg);
    k_scan1<<<NBLK, 256, 0, stream>>>(deg, offs, cur, bsum);
    k_scan2<<<1, 256, 0, stream>>>(bsum, boff, offs);
    k_scan3<<<NBLK, 256, 0, stream>>>(boff, offs, cur);
    k_scatter<<<(ETOT + 255) / 256, 256, 0, stream>>>(dstArr, cur, eid);

    bf16* h1 = bufA;
    bf16* x2 = (bf16*)bufB;
    k_gemm1<<<NN / TM, 256, 0, stream>>>(x, W1, aw_s1, aw_d1, h1, as1, ad1);
    k_agg1<<<NN, 256, 0, stream>>>(srcArr, offs, eid, h1, as1, ad1, b1, x2);

    bf16* h2 = bufA;  // h1 dead after agg1
    k_gemm2<<<NN / TM, 128, 0, stream>>>(x2, W2, aw_s2, aw_d2, h2, as2, ad2);

    float* hf = (float*)bufB;  // x2 dead after gemm2
    k_agg2<<<NN, 128, 0, stream>>>(srcArr, offs, eid, h2, as2, ad2, b2, hf);

    k_pool<<<NN, 128, 0, stream>>>(hf, batch, pooled, cnt);
    k_final<<<2, 256, 0, stream>>>(pooled, cnt, Wl, bl, (float*)d_out);
}

// Round 9
// 633.847 us; speedup vs baseline: 1.4147x; 1.0227x over previous
//
#include <hip/hip_runtime.h>
#include <hip/hip_bf16.h>

#define NN 50000
#define EE 800000
#define ETOT 850000
#define BB 512
#define NBLK 196   // ceil(NN/256)
#define TM 8       // nodes per GEMM block (50000 = 6250*8)

typedef __hip_bfloat16 bf16;

__device__ __forceinline__ float b2f(bf16 v) { return __bfloat162float(v); }
__device__ __forceinline__ float us2f(unsigned short u) {
    return __uint_as_float(((unsigned int)u) << 16);
}

// ---------------- zeroing ----------------
__global__ void k_zeroi(int* __restrict__ p, int n) {
    int i = blockIdx.x * blockDim.x + threadIdx.x;
    if (i < n) p[i] = 0;
}
__global__ void k_zerof(float* __restrict__ p, int n) {
    int i = blockIdx.x * blockDim.x + threadIdx.x;
    if (i < n) p[i] = 0.f;
}

// ---------------- CSR build ----------------
__global__ void k_count(const int* __restrict__ dstArr, int* __restrict__ deg) {
    int e = blockIdx.x * blockDim.x + threadIdx.x;
    if (e >= ETOT) return;
    int d = (e < EE) ? dstArr[e] : (e - EE);
    d = min(max(d, 0), NN - 1);
    atomicAdd(&deg[d], 1);
}

__global__ void k_scan1(const int* __restrict__ deg, int* __restrict__ offs,
                        int* __restrict__ cur, int* __restrict__ bsum) {
    __shared__ int s[256];
    int t = threadIdx.x;
    int i = blockIdx.x * 256 + t;
    int v = (i < NN) ? deg[i] : 0;
    s[t] = v;
    __syncthreads();
    for (int o = 1; o < 256; o <<= 1) {
        int tv = (t >= o) ? s[t - o] : 0;
        __syncthreads();
        s[t] += tv;
        __syncthreads();
    }
    int excl = s[t] - v;
    if (i < NN) { offs[i] = excl; cur[i] = excl; }
    if (t == 255) bsum[blockIdx.x] = s[255];
}

__global__ void k_scan2(const int* __restrict__ bsum, int* __restrict__ boff,
                        int* __restrict__ offs) {
    __shared__ int s[256];
    int t = threadIdx.x;
    int v = (t < NBLK) ? bsum[t] : 0;
    s[t] = v;
    __syncthreads();
    for (int o = 1; o < 256; o <<= 1) {
        int tv = (t >= o) ? s[t - o] : 0;
        __syncthreads();
        s[t] += tv;
        __syncthreads();
    }
    if (t < NBLK) boff[t] = s[t] - v;
    if (t == 0) offs[NN] = ETOT;
}

__global__ void k_scan3(const int* __restrict__ boff, int* __restrict__ offs,
                        int* __restrict__ cur) {
    int i = blockIdx.x * 256 + threadIdx.x;
    if (i < NN) {
        int b = boff[blockIdx.x];
        offs[i] += b;
        cur[i] += b;
    }
}

__global__ void k_scatter(const int* __restrict__ dstArr, int* __restrict__ cur,
                          int* __restrict__ eid) {
    int e = blockIdx.x * blockDim.x + threadIdx.x;
    if (e >= ETOT) return;
    int d = (e < EE) ? dstArr[e] : (e - EE);
    d = min(max(d, 0), NN - 1);
    int p = atomicAdd(&cur[d], 1);
    if (p >= 0 && p < ETOT) eid[p] = e;
}

// ---------------- Layer 1 GEMM (register-tiled, TM=8) ----------------
__global__ void k_gemm1(const float* __restrict__ x, const float* __restrict__ W1,
                        const float* __restrict__ aw_s, const float* __restrict__ aw_d,
                        bf16* __restrict__ h1, float* __restrict__ as1,
                        float* __restrict__ ad1) {
    int n0 = blockIdx.x * TM;
    int t = threadIdx.x;
    __shared__ float xs[TM * 128];   // 4 KB
    {
        int n = t >> 5;
        int c4 = t & 31;
        float4 v = *(const float4*)&x[(size_t)(n0 + n) * 128 + c4 * 4];
        *(float4*)&xs[n * 128 + c4 * 4] = v;
    }
    __syncthreads();
    float acc[TM];
#pragma unroll
    for (int n = 0; n < TM; n++) acc[n] = 0.f;
    for (int kc = 0; kc < 32; kc++) {
        float w0 = W1[(kc * 4 + 0) * 256 + t];
        float w1 = W1[(kc * 4 + 1) * 256 + t];
        float w2 = W1[(kc * 4 + 2) * 256 + t];
        float w3 = W1[(kc * 4 + 3) * 256 + t];
#pragma unroll
        for (int n = 0; n < TM; n++) {
            float4 xv = *(const float4*)&xs[n * 128 + kc * 4];
            acc[n] += xv.x * w0;
            acc[n] += xv.y * w1;
            acc[n] += xv.z * w2;
            acc[n] += xv.w * w3;
        }
    }
    float s_t = aw_s[t], d_t = aw_d[t];
    int h = t >> 6, ln = t & 63;
#pragma unroll
    for (int n = 0; n < TM; n++) {
        h1[(size_t)(n0 + n) * 256 + t] = __float2bfloat16(acc[n]);
        float ps = acc[n] * s_t;
        float pd = acc[n] * d_t;
        for (int o = 32; o > 0; o >>= 1) {
            ps += __shfl_down(ps, o);
            pd += __shfl_down(pd, o);
        }
        if (ln == 0) {
            as1[(n0 + n) * 4 + h] = ps;
            ad1[(n0 + n) * 4 + h] = pd;
        }
    }
}

// ---------------- Layer 1 softmax weights: one thread per (node, head) ----------------
// alpha1[p*4+h] = normalized attention weight for CSR position p, head h
__global__ void k_soft1(const int* __restrict__ srcArr, const int* __restrict__ offs,
                        const int* __restrict__ eid, const float* __restrict__ as1,
                        const float* __restrict__ ad1, float* __restrict__ alpha1) {
    int gid = blockIdx.x * blockDim.x + threadIdx.x;
    int n = gid >> 2, h = gid & 3;
    if (n >= NN) return;
    int beg = offs[n], end = offs[n + 1];
    beg = min(max(beg, 0), ETOT);
    end = min(max(end, beg), ETOT);
    float adh = ad1[n * 4 + h];
    float m = -1e30f;
    for (int p = beg; p < end; p++) {
        int e = eid[p];
        e = min(max(e, 0), ETOT - 1);
        int s = (e < EE) ? srcArr[e] : (e - EE);
        s = min(max(s, 0), NN - 1);
        float ev = as1[s * 4 + h] + adh;
        ev = ev > 0.f ? ev : 0.2f * ev;        // leaky_relu(0.2)
        alpha1[(size_t)p * 4 + h] = ev;
        m = fmaxf(m, ev);
    }
    float sum = 0.f;
    for (int p = beg; p < end; p++) {
        float wgt = __expf(alpha1[(size_t)p * 4 + h] - m);
        alpha1[(size_t)p * 4 + h] = wgt;
        sum += wgt;
    }
    float inv = 1.f / fmaxf(sum, 1e-30f);
    for (int p = beg; p < end; p++)
        alpha1[(size_t)p * 4 + h] *= inv;
}

// ---------------- Layer 1 gather (lean: cvt+fma only) ----------------
__global__ void k_gather1(const int* __restrict__ srcArr, const int* __restrict__ offs,
                          const int* __restrict__ eid, const bf16* __restrict__ h1,
                          const float* __restrict__ alpha1, const float* __restrict__ b1,
                          bf16* __restrict__ x2) {
    int n = blockIdx.x;
    int t = threadIdx.x;
    int h = t >> 6;
    int beg = offs[n], end = offs[n + 1];
    beg = min(max(beg, 0), ETOT);
    end = min(max(end, beg), ETOT);
    float acc = 0.f;
    __shared__ int ls[64];
    __shared__ float la[64 * 4];
    for (int cb = beg; cb < end; cb += 64) {
        int cnt = min(64, end - cb);
        __syncthreads();
        if (t < cnt) {
            int e = eid[cb + t];
            e = min(max(e, 0), ETOT - 1);
            int s = (e < EE) ? srcArr[e] : (e - EE);
            ls[t] = min(max(s, 0), NN - 1);
            *(float4*)&la[t * 4] = *(const float4*)&alpha1[(size_t)(cb + t) * 4];
        }
        __syncthreads();
        for (int j = 0; j < cnt; j++) {
            acc += la[j * 4 + h] * b2f(h1[(size_t)ls[j] * 256 + t]);
        }
    }
    float r = acc + b1[t];
    x2[(size_t)n * 256 + t] = __float2bfloat16(r > 0.f ? r : (__expf(r) - 1.f));  // ELU
}

// ---------------- Layer 2 GEMM (register-tiled, TM=8, bf16 input) ----------------
__global__ void k_gemm2(const bf16* __restrict__ x2, const float* __restrict__ W2,
                        const float* __restrict__ aw_s, const float* __restrict__ aw_d,
                        bf16* __restrict__ h2, float* __restrict__ as2,
                        float* __restrict__ ad2) {
    int n0 = blockIdx.x * TM;
    int t = threadIdx.x;
    __shared__ float xs[TM * 256];   // 8 KB
    {
        int n = t >> 4;
        int c = t & 15;
        const unsigned short* xr =
            (const unsigned short*)x2 + (size_t)(n0 + n) * 256 + c * 16;
#pragma unroll
        for (int k4 = 0; k4 < 4; k4++) {
            ushort4 u = *(const ushort4*)(xr + k4 * 4);
            float4 v;
            v.x = us2f(u.x); v.y = us2f(u.y); v.z = us2f(u.z); v.w = us2f(u.w);
            *(float4*)&xs[n * 256 + c * 16 + k4 * 4] = v;
        }
    }
    __syncthreads();
    float acc[TM];
#pragma unroll
    for (int n = 0; n < TM; n++) acc[n] = 0.f;
    for (int kc = 0; kc < 64; kc++) {
        float w0 = W2[(kc * 4 + 0) * 128 + t];
        float w1 = W2[(kc * 4 + 1) * 128 + t];
        float w2 = W2[(kc * 4 + 2) * 128 + t];
        float w3 = W2[(kc * 4 + 3) * 128 + t];
#pragma unroll
        for (int n = 0; n < TM; n++) {
            float4 xv = *(const float4*)&xs[n * 256 + kc * 4];
            acc[n] += xv.x * w0;
            acc[n] += xv.y * w1;
            acc[n] += xv.z * w2;
            acc[n] += xv.w * w3;
        }
    }
    __shared__ float redS[TM][2];
    __shared__ float redD[TM][2];
    float s_t = aw_s[t], d_t = aw_d[t];
    int wv = t >> 6, ln = t & 63;
#pragma unroll
    for (int n = 0; n < TM; n++) {
        h2[(size_t)(n0 + n) * 128 + t] = __float2bfloat16(acc[n]);
        float ps = acc[n] * s_t;
        float pd = acc[n] * d_t;
        for (int o = 32; o > 0; o >>= 1) {
            ps += __shfl_down(ps, o);
            pd += __shfl_down(pd, o);
        }
        if (ln == 0) { redS[n][wv] = ps; redD[n][wv] = pd; }
    }
    __syncthreads();
    if (t < TM) {
        as2[n0 + t] = redS[t][0] + redS[t][1];
        ad2[n0 + t] = redD[t][0] + redD[t][1];
    }
}

// ---------------- Layer 2 softmax weights: one thread per node (H=1) ----------------
__global__ void k_soft2(const int* __restrict__ srcArr, const int* __restrict__ offs,
                        const int* __restrict__ eid, const float* __restrict__ as2,
                        const float* __restrict__ ad2, float* __restrict__ alpha2) {
    int n = blockIdx.x * blockDim.x + threadIdx.x;
    if (n >= NN) return;
    int beg = offs[n], end = offs[n + 1];
    beg = min(max(beg, 0), ETOT);
    end = min(max(end, beg), ETOT);
    float adn = ad2[n];
    float m = -1e30f;
    for (int p = beg; p < end; p++) {
        int e = eid[p];
        e = min(max(e, 0), ETOT - 1);
        int s = (e < EE) ? srcArr[e] : (e - EE);
        s = min(max(s, 0), NN - 1);
        float ev = as2[s] + adn;
        ev = ev > 0.f ? ev : 0.2f * ev;
        alpha2[p] = ev;
        m = fmaxf(m, ev);
    }
    float sum = 0.f;
    for (int p = beg; p < end; p++) {
        float wgt = __expf(alpha2[p] - m);
        alpha2[p] = wgt;
        sum += wgt;
    }
    float inv = 1.f / fmaxf(sum, 1e-30f);
    for (int p = beg; p < end; p++) alpha2[p] *= inv;
}

// ---------------- Layer 2 gather + fused mean-pool accumulate ----------------
__global__ void k_gather2(const int* __restrict__ srcArr, const int* __restrict__ offs,
                          const int* __restrict__ eid, const bf16* __restrict__ h2,
                          const float* __restrict__ alpha2, const float* __restrict__ b2,
                          const int* __restrict__ batch, float* __restrict__ pooled) {
    int n = blockIdx.x;
    int t = threadIdx.x;
    int beg = offs[n], end = offs[n + 1];
    beg = min(max(beg, 0), ETOT);
    end = min(max(end, beg), ETOT);
    float acc = 0.f;
    __shared__ int ls[64];
    __shared__ float la[64];
    for (int cb = beg; cb < end; cb += 64) {
        int cnt = min(64, end - cb);
        __syncthreads();
        if (t < 64 && t < cnt) {
            int e = eid[cb + t];
            e = min(max(e, 0), ETOT - 1);
            int s = (e < EE) ? srcArr[e] : (e - EE);
            ls[t] = min(max(s, 0), NN - 1);
            la[t] = alpha2[cb + t];
        }
        __syncthreads();
        for (int j = 0; j < cnt; j++) {
            acc += la[j] * b2f(h2[(size_t)ls[j] * 128 + t]);
        }
    }
    float r = acc + b2[t];
    r = r > 0.f ? r : (__expf(r) - 1.f);  // ELU
    int b = batch[n];
    b = min(max(b, 0), BB - 1);
    atomicAdd(&pooled[b * 128 + t], r);
}

// ---------------- per-graph node counts ----------------
__global__ void k_cnt(const int* __restrict__ batch, int* __restrict__ cnt) {
    int n = blockIdx.x * blockDim.x + threadIdx.x;
    if (n >= NN) return;
    int b = batch[n];
    b = min(max(b, 0), BB - 1);
    atomicAdd(&cnt[b], 1);
}

// ---------------- final linear + sigmoid (f32 output) ----------------
__global__ void k_final(const float* __restrict__ pooled, const int* __restrict__ cnt,
                        const float* __restrict__ Wl, const float* __restrict__ bl,
                        float* __restrict__ out) {
    int b = blockIdx.x * blockDim.x + threadIdx.x;
    if (b >= BB) return;
    float acc = 0.f;
    for (int k = 0; k < 128; k++) acc += pooled[b * 128 + k] * Wl[k];
    int c = cnt[b];
    float cf = (float)(c > 0 ? c : 1);
    float g = acc / cf + bl[0];
    out[b] = 1.f / (1.f + __expf(-g));
}

extern "C" void kernel_launch(void* const* d_in, const int* in_sizes, int n_in,
                              void* d_out, int out_size, void* d_ws, size_t ws_size,
                              hipStream_t stream) {
    const float* x = (const float*)d_in[0];
    const int* ei = (const int*)d_in[1];
    const int* batch = (const int*)d_in[2];
    const float* W1 = (const float*)d_in[3];
    const float* aw_s1 = (const float*)d_in[4];
    const float* aw_d1 = (const float*)d_in[5];
    const float* b1 = (const float*)d_in[6];
    const float* W2 = (const float*)d_in[7];
    const float* aw_s2 = (const float*)d_in[8];
    const float* aw_d2 = (const float*)d_in[9];
    const float* b2 = (const float*)d_in[10];
    const float* Wl = (const float*)d_in[11];
    const float* bl = (const float*)d_in[12];
    const int* srcArr = ei;
    const int* dstArr = ei + EE;

    char* w = (char*)d_ws;
    size_t off = 0;
    auto alloc = [&](size_t bytes) -> void* {
        void* p = (void*)(w + off);
        off = (off + bytes + 255) & ~(size_t)255;
        return p;
    };
    bf16* bufA = (bf16*)alloc((size_t)NN * 256 * 2);   // h1 [N,256]; later h2 [N,128]
    bf16* bufB = (bf16*)alloc((size_t)NN * 256 * 2);   // x2 [N,256]
    float* alpha1 = (float*)alloc((size_t)ETOT * 4 * 4);  // 13.6 MB; reused as alpha2
    float* as1 = (float*)alloc((size_t)NN * 4 * 4);
    float* ad1 = (float*)alloc((size_t)NN * 4 * 4);
    float* as2 = (float*)alloc((size_t)NN * 4);
    float* ad2 = (float*)alloc((size_t)NN * 4);
    int* deg = (int*)alloc((size_t)NN * 4);
    int* offs = (int*)alloc((size_t)(NN + 1) * 4);
    int* cur = (int*)alloc((size_t)NN * 4);
    int* eid = (int*)alloc((size_t)ETOT * 4);
    int* bsum = (int*)alloc((size_t)NBLK * 4);
    int* boff = (int*)alloc((size_t)NBLK * 4);
    float* pooled = (float*)alloc((size_t)BB * 128 * 4);
    int* cnt = (int*)alloc((size_t)BB * 4);
    (void)ws_size;

    k_zeroi<<<NBLK, 256, 0, stream>>>(deg, NN);
    k_zerof<<<(BB * 128 + 255) / 256, 256, 0, stream>>>(pooled, BB * 128);
    k_zeroi<<<(BB + 255) / 256, 256, 0, stream>>>(cnt, BB);

    k_count<<<(ETOT + 255) / 256, 256, 0, stream>>>(dstArr, deg);
    k_scan1<<<NBLK, 256, 0, stream>>>(deg, offs, cur, bsum);
    k_scan2<<<1, 256, 0, stream>>>(bsum, boff, offs);
    k_scan3<<<NBLK, 256, 0, stream>>>(boff, offs, cur);
    k_scatter<<<(ETOT + 255) / 256, 256, 0, stream>>>(dstArr, cur, eid);
    k_cnt<<<NBLK, 256, 0, stream>>>(batch, cnt);

    bf16* h1 = bufA;
    bf16* x2 = bufB;
    k_gemm1<<<NN / TM, 256, 0, stream>>>(x, W1, aw_s1, aw_d1, h1, as1, ad1);
    k_soft1<<<(NN * 4 + 255) / 256, 256, 0, stream>>>(srcArr, offs, eid, as1, ad1, alpha1);
    k_gather1<<<NN, 256, 0, stream>>>(srcArr, offs, eid, h1, alpha1, b1, x2);

    bf16* h2 = bufA;  // h1 dead after gather1
    k_gemm2<<<NN / TM, 128, 0, stream>>>(x2, W2, aw_s2, aw_d2, h2, as2, ad2);

    float* alpha2 = alpha1;  // alpha1 dead after gather1
    k_soft2<<<NBLK, 256, 0, stream>>>(srcArr, offs, eid, as2, ad2, alpha2);
    k_gather2<<<NN, 128, 0, stream>>>(srcArr, offs, eid, h2, alpha2, b2, batch, pooled);

    k_final<<<2, 256, 0, stream>>>(pooled, cnt, Wl, bl, (float*)d_out);
}

// Round 11
// 517.901 us; speedup vs baseline: 1.7314x; 1.2239x over previous
//
#include <hip/hip_runtime.h>
#include <hip/hip_bf16.h>

#define NN 50000
#define EE 800000
#define ETOT 850000
#define BB 512
#define NBLK 196   // ceil(NN/256)

typedef __hip_bfloat16 bf16;
typedef __attribute__((ext_vector_type(8))) __bf16 v8bf;
typedef __attribute__((ext_vector_type(4))) float f32x4;

__device__ __forceinline__ float b2f(bf16 v) { return __bfloat162float(v); }
__device__ __forceinline__ float lo2f(unsigned int u) {
    return __uint_as_float(u << 16);
}
__device__ __forceinline__ float hi2f(unsigned int u) {
    return __uint_as_float(u & 0xffff0000u);
}
__device__ __forceinline__ unsigned short f2bfbits(float f) {
    bf16 h = __float2bfloat16(f);
    return *reinterpret_cast<unsigned short*>(&h);
}

// ---------------- zeroing ----------------
__global__ void k_zeroi(int* __restrict__ p, int n) {
    int i = blockIdx.x * blockDim.x + threadIdx.x;
    if (i < n) p[i] = 0;
}
__global__ void k_zerof(float* __restrict__ p, int n) {
    int i = blockIdx.x * blockDim.x + threadIdx.x;
    if (i < n) p[i] = 0.f;
}

// ---------------- weight transpose+cvt (launched AFTER k_scatter; aliases cur) ----------------
// wt1[c][k] = W1[k][c]  (256 cols, 128 k)
__global__ void k_cvtw1(const float* __restrict__ W1, bf16* __restrict__ wt1) {
    int idx = blockIdx.x * blockDim.x + threadIdx.x;
    if (idx >= 256 * 128) return;
    int c = idx >> 7, k = idx & 127;
    wt1[idx] = __float2bfloat16(W1[k * 256 + c]);
}
// wt2[c][k] = W2[k][c]  (128 cols, 256 k)
__global__ void k_cvtw2(const float* __restrict__ W2, bf16* __restrict__ wt2) {
    int idx = blockIdx.x * blockDim.x + threadIdx.x;
    if (idx >= 128 * 256) return;
    int c = idx >> 8, k = idx & 255;
    wt2[idx] = __float2bfloat16(W2[k * 128 + c]);
}

// ---------------- CSR build ----------------
__global__ void k_count(const int* __restrict__ dstArr, int* __restrict__ deg) {
    int e = blockIdx.x * blockDim.x + threadIdx.x;
    if (e >= ETOT) return;
    int d = (e < EE) ? dstArr[e] : (e - EE);
    d = min(max(d, 0), NN - 1);
    atomicAdd(&deg[d], 1);
}

__global__ void k_scan1(const int* __restrict__ deg, int* __restrict__ offs,
                        int* __restrict__ cur, int* __restrict__ bsum) {
    __shared__ int s[256];
    int t = threadIdx.x;
    int i = blockIdx.x * 256 + t;
    int v = (i < NN) ? deg[i] : 0;
    s[t] = v;
    __syncthreads();
    for (int o = 1; o < 256; o <<= 1) {
        int tv = (t >= o) ? s[t - o] : 0;
        __syncthreads();
        s[t] += tv;
        __syncthreads();
    }
    int excl = s[t] - v;
    if (i < NN) { offs[i] = excl; cur[i] = excl; }
    if (t == 255) bsum[blockIdx.x] = s[255];
}

__global__ void k_scan2(const int* __restrict__ bsum, int* __restrict__ boff,
                        int* __restrict__ offs) {
    __shared__ int s[256];
    int t = threadIdx.x;
    int v = (t < NBLK) ? bsum[t] : 0;
    s[t] = v;
    __syncthreads();
    for (int o = 1; o < 256; o <<= 1) {
        int tv = (t >= o) ? s[t - o] : 0;
        __syncthreads();
        s[t] += tv;
        __syncthreads();
    }
    if (t < NBLK) boff[t] = s[t] - v;
    if (t == 0) offs[NN] = ETOT;
}

__global__ void k_scan3(const int* __restrict__ boff, int* __restrict__ offs,
                        int* __restrict__ cur) {
    int i = blockIdx.x * 256 + threadIdx.x;
    if (i < NN) {
        int b = boff[blockIdx.x];
        offs[i] += b;
        cur[i] += b;
    }
}

__global__ void k_scatter(const int* __restrict__ dstArr, int* __restrict__ cur,
                          int* __restrict__ eid) {
    int e = blockIdx.x * blockDim.x + threadIdx.x;
    if (e >= ETOT) return;
    int d = (e < EE) ? dstArr[e] : (e - EE);
    d = min(max(d, 0), NN - 1);
    int p = atomicAdd(&cur[d], 1);
    if (p >= 0 && p < ETOT) eid[p] = e;
}

// ---------------- Layer 1 GEMM via MFMA (f32 x staged+converted in-kernel) ----------------
// C[64 nodes x 256 cols] per block; 4 waves, each 16 nodes x 256 cols.
__global__ void k_gemm1(const float* __restrict__ x, const bf16* __restrict__ wt1,
                        const float* __restrict__ aw_s, const float* __restrict__ aw_d,
                        bf16* __restrict__ h1, float* __restrict__ as1,
                        float* __restrict__ ad1) {
    int n0 = blockIdx.x * 64;
    int t = threadIdx.x;
    __shared__ bf16 xs[64 * 136];   // 64 rows x (128+8) bf16, padded
    // stage: 64 rows x 32 float4 chunks -> bf16x4
    for (int i = 0; i < 8; i++) {
        int idx = t + 256 * i;          // 0..2047
        int r = idx >> 5, c4 = idx & 31;
        float4 v = make_float4(0.f, 0.f, 0.f, 0.f);
        if (n0 + r < NN) v = *(const float4*)(x + (size_t)(n0 + r) * 128 + c4 * 4);
        ushort4 o;
        o.x = f2bfbits(v.x); o.y = f2bfbits(v.y);
        o.z = f2bfbits(v.z); o.w = f2bfbits(v.w);
        *(ushort4*)(&xs[r * 136 + c4 * 4]) = o;
    }
    __syncthreads();

    int wv = t >> 6, lane = t & 63;
    int q = lane >> 4, r16 = lane & 15;
    int nw = wv * 16;

    f32x4 acc[16];
#pragma unroll
    for (int ct = 0; ct < 16; ct++) acc[ct] = (f32x4){0.f, 0.f, 0.f, 0.f};

#pragma unroll
    for (int kt = 0; kt < 4; kt++) {
        v8bf va = *(const v8bf*)(&xs[(nw + r16) * 136 + kt * 32 + q * 8]);
#pragma unroll
        for (int ct = 0; ct < 16; ct++) {
            v8bf vb = *(const v8bf*)(wt1 + (size_t)(ct * 16 + r16) * 128 + kt * 32 + q * 8);
            acc[ct] = __builtin_amdgcn_mfma_f32_16x16x32_bf16(va, vb, acc[ct], 0, 0, 0);
        }
    }

#pragma unroll
    for (int reg = 0; reg < 4; reg++) {
        int node = n0 + nw + q * 4 + reg;
        bool ok = node < NN;
#pragma unroll
        for (int ct = 0; ct < 16; ct++) {
            if (ok) h1[(size_t)node * 256 + ct * 16 + r16] = __float2bfloat16(acc[ct][reg]);
        }
#pragma unroll
        for (int h = 0; h < 4; h++) {
            float ps = 0.f, pd = 0.f;
#pragma unroll
            for (int i = 0; i < 4; i++) {
                int ct = h * 4 + i;
                int col = ct * 16 + r16;
                float v = acc[ct][reg];
                ps += v * aw_s[col];
                pd += v * aw_d[col];
            }
            for (int mask = 1; mask <= 8; mask <<= 1) {
                ps += __shfl_xor(ps, mask);
                pd += __shfl_xor(pd, mask);
            }
            if (r16 == 0 && ok) {
                as1[node * 4 + h] = ps;
                ad1[node * 4 + h] = pd;
            }
        }
    }
}

// ---------------- Layer 1 softmax weights ----------------
__global__ void k_soft1(const int* __restrict__ srcArr, const int* __restrict__ offs,
                        const int* __restrict__ eid, const float* __restrict__ as1,
                        const float* __restrict__ ad1, float* __restrict__ alpha1) {
    int gid = blockIdx.x * blockDim.x + threadIdx.x;
    int n = gid >> 2, h = gid & 3;
    if (n >= NN) return;
    int beg = offs[n], end = offs[n + 1];
    beg = min(max(beg, 0), ETOT);
    end = min(max(end, beg), ETOT);
    float adh = ad1[n * 4 + h];
    float m = -1e30f;
    for (int p = beg; p < end; p++) {
        int e = eid[p];
        e = min(max(e, 0), ETOT - 1);
        int s = (e < EE) ? srcArr[e] : (e - EE);
        s = min(max(s, 0), NN - 1);
        float ev = as1[s * 4 + h] + adh;
        ev = ev > 0.f ? ev : 0.2f * ev;        // leaky_relu(0.2)
        alpha1[(size_t)p * 4 + h] = ev;
        m = fmaxf(m, ev);
    }
    float sum = 0.f;
    for (int p = beg; p < end; p++) {
        float wgt = __expf(alpha1[(size_t)p * 4 + h] - m);
        alpha1[(size_t)p * 4 + h] = wgt;
        sum += wgt;
    }
    float inv = 1.f / fmaxf(sum, 1e-30f);
    for (int p = beg; p < end; p++)
        alpha1[(size_t)p * 4 + h] *= inv;
}

// ---------------- Layer 1 gather: one wave per node, 4 cols/thread ----------------
__global__ void k_gather1(const int* __restrict__ srcArr, const int* __restrict__ offs,
                          const int* __restrict__ eid, const bf16* __restrict__ h1,
                          const float* __restrict__ alpha1, const float* __restrict__ b1,
                          bf16* __restrict__ x2) {
    int n = blockIdx.x;
    int t = threadIdx.x;        // 0..63
    int h = t >> 4;             // head of cols t*4..t*4+3
    int beg = offs[n], end = offs[n + 1];
    beg = min(max(beg, 0), ETOT);
    end = min(max(end, beg), ETOT);
    float a0 = 0.f, a1 = 0.f, a2 = 0.f, a3 = 0.f;
    __shared__ int ls[64];
    __shared__ float la[64 * 4];
    const unsigned short* h1u = (const unsigned short*)h1;
    for (int cb = beg; cb < end; cb += 64) {
        int cnt = min(64, end - cb);
        __syncthreads();
        if (t < cnt) {
            int e = eid[cb + t];
            e = min(max(e, 0), ETOT - 1);
            int s = (e < EE) ? srcArr[e] : (e - EE);
            ls[t] = min(max(s, 0), NN - 1);
            *(float4*)&la[t * 4] = *(const float4*)&alpha1[(size_t)(cb + t) * 4];
        }
        __syncthreads();
        for (int j = 0; j < cnt; j++) {
            int s = ls[j];
            float a = la[j * 4 + h];
            uint2 u = *(const uint2*)(h1u + (size_t)s * 256 + t * 4);
            a0 = fmaf(a, lo2f(u.x), a0);
            a1 = fmaf(a, hi2f(u.x), a1);
            a2 = fmaf(a, lo2f(u.y), a2);
            a3 = fmaf(a, hi2f(u.y), a3);
        }
    }
    int c = t * 4;
    float r0 = a0 + b1[c + 0];
    float r1 = a1 + b1[c + 1];
    float r2 = a2 + b1[c + 2];
    float r3 = a3 + b1[c + 3];
    r0 = r0 > 0.f ? r0 : (__expf(r0) - 1.f);
    r1 = r1 > 0.f ? r1 : (__expf(r1) - 1.f);
    r2 = r2 > 0.f ? r2 : (__expf(r2) - 1.f);
    r3 = r3 > 0.f ? r3 : (__expf(r3) - 1.f);
    bf16* xr = x2 + (size_t)n * 256 + c;
    xr[0] = __float2bfloat16(r0);
    xr[1] = __float2bfloat16(r1);
    xr[2] = __float2bfloat16(r2);
    xr[3] = __float2bfloat16(r3);
}

// ---------------- Layer 2 GEMM via MFMA ----------------
__global__ void k_gemm2(const bf16* __restrict__ x2, const bf16* __restrict__ wt2,
                        const float* __restrict__ aw_s, const float* __restrict__ aw_d,
                        bf16* __restrict__ h2, float* __restrict__ as2,
                        float* __restrict__ ad2) {
    int n0 = blockIdx.x * 64;
    int t = threadIdx.x;
    __shared__ bf16 xs[64 * 264];   // 64 rows x (256+8) bf16
    for (int i = 0; i < 8; i++) {
        int idx = t + 256 * i;          // 0..2047
        int r = idx >> 5, c8 = idx & 31;
        uint4 v;
        if (n0 + r < NN) v = *(const uint4*)(x2 + (size_t)(n0 + r) * 256 + c8 * 8);
        else             v = make_uint4(0, 0, 0, 0);
        *(uint4*)(&xs[r * 264 + c8 * 8]) = v;
    }
    __syncthreads();

    int wv = t >> 6, lane = t & 63;
    int q = lane >> 4, r16 = lane & 15;
    int nw = wv * 16;

    f32x4 acc[8];
#pragma unroll
    for (int ct = 0; ct < 8; ct++) acc[ct] = (f32x4){0.f, 0.f, 0.f, 0.f};

#pragma unroll
    for (int kt = 0; kt < 8; kt++) {
        v8bf va = *(const v8bf*)(&xs[(nw + r16) * 264 + kt * 32 + q * 8]);
#pragma unroll
        for (int ct = 0; ct < 8; ct++) {
            v8bf vb = *(const v8bf*)(wt2 + (size_t)(ct * 16 + r16) * 256 + kt * 32 + q * 8);
            acc[ct] = __builtin_amdgcn_mfma_f32_16x16x32_bf16(va, vb, acc[ct], 0, 0, 0);
        }
    }

#pragma unroll
    for (int reg = 0; reg < 4; reg++) {
        int node = n0 + nw + q * 4 + reg;
        bool ok = node < NN;
        float ps = 0.f, pd = 0.f;
#pragma unroll
        for (int ct = 0; ct < 8; ct++) {
            int col = ct * 16 + r16;
            float v = acc[ct][reg];
            if (ok) h2[(size_t)node * 128 + col] = __float2bfloat16(v);
            ps += v * aw_s[col];
            pd += v * aw_d[col];
        }
        for (int mask = 1; mask <= 8; mask <<= 1) {
            ps += __shfl_xor(ps, mask);
            pd += __shfl_xor(pd, mask);
        }
        if (r16 == 0 && ok) {
            as2[node] = ps;
            ad2[node] = pd;
        }
    }
}

// ---------------- Layer 2 softmax weights ----------------
__global__ void k_soft2(const int* __restrict__ srcArr, const int* __restrict__ offs,
                        const int* __restrict__ eid, const float* __restrict__ as2,
                        const float* __restrict__ ad2, float* __restrict__ alpha2) {
    int n = blockIdx.x * blockDim.x + threadIdx.x;
    if (n >= NN) return;
    int beg = offs[n], end = offs[n + 1];
    beg = min(max(beg, 0), ETOT);
    end = min(max(end, beg), ETOT);
    float adn = ad2[n];
    float m = -1e30f;
    for (int p = beg; p < end; p++) {
        int e = eid[p];
        e = min(max(e, 0), ETOT - 1);
        int s = (e < EE) ? srcArr[e] : (e - EE);
        s = min(max(s, 0), NN - 1);
        float ev = as2[s] + adn;
        ev = ev > 0.f ? ev : 0.2f * ev;
        alpha2[p] = ev;
        m = fmaxf(m, ev);
    }
    float sum = 0.f;
    for (int p = beg; p < end; p++) {
        float wgt = __expf(alpha2[p] - m);
        alpha2[p] = wgt;
        sum += wgt;
    }
    float inv = 1.f / fmaxf(sum, 1e-30f);
    for (int p = beg; p < end; p++) alpha2[p] *= inv;
}

// ---------------- Layer 2 gather + fused mean-pool: one wave per node ----------------
__global__ void k_gather2(const int* __restrict__ srcArr, const int* __restrict__ offs,
                          const int* __restrict__ eid, const bf16* __restrict__ h2,
                          const float* __restrict__ alpha2, const float* __restrict__ b2,
                          const int* __restrict__ batch, float* __restrict__ pooled) {
    int n = blockIdx.x;
    int t = threadIdx.x;        // 0..63
    int beg = offs[n], end = offs[n + 1];
    beg = min(max(beg, 0), ETOT);
    end = min(max(end, beg), ETOT);
    float a0 = 0.f, a1 = 0.f;
    __shared__ int ls[64];
    __shared__ float la[64];
    const unsigned short* h2u = (const unsigned short*)h2;
    for (int cb = beg; cb < end; cb += 64) {
        int cnt = min(64, end - cb);
        __syncthreads();
        if (t < cnt) {
            int e = eid[cb + t];
            e = min(max(e, 0), ETOT - 1);
            int s = (e < EE) ? srcArr[e] : (e - EE);
            ls[t] = min(max(s, 0), NN - 1);
            la[t] = alpha2[cb + t];
        }
        __syncthreads();
        for (int j = 0; j < cnt; j++) {
            int s = ls[j];
            float a = la[j];
            unsigned int u = *(const unsigned int*)(h2u + (size_t)s * 128 + t * 2);
            a0 = fmaf(a, lo2f(u), a0);
            a1 = fmaf(a, hi2f(u), a1);
        }
    }
    int c = t * 2;
    float r0 = a0 + b2[c + 0];
    float r1 = a1 + b2[c + 1];
    r0 = r0 > 0.f ? r0 : (__expf(r0) - 1.f);
    r1 = r1 > 0.f ? r1 : (__expf(r1) - 1.f);
    int b = batch[n];
    b = min(max(b, 0), BB - 1);
    atomicAdd(&pooled[b * 128 + c + 0], r0);
    atomicAdd(&pooled[b * 128 + c + 1], r1);
}

// ---------------- per-graph node counts ----------------
__global__ void k_cnt(const int* __restrict__ batch, int* __restrict__ cnt) {
    int n = blockIdx.x * blockDim.x + threadIdx.x;
    if (n >= NN) return;
    int b = batch[n];
    b = min(max(b, 0), BB - 1);
    atomicAdd(&cnt[b], 1);
}

// ---------------- final linear + sigmoid (f32 output) ----------------
__global__ void k_final(const float* __restrict__ pooled, const int* __restrict__ cnt,
                        const float* __restrict__ Wl, const float* __restrict__ bl,
                        float* __restrict__ out) {
    int b = blockIdx.x * blockDim.x + threadIdx.x;
    if (b >= BB) return;
    float acc = 0.f;
    for (int k = 0; k < 128; k++) acc += pooled[b * 128 + k] * Wl[k];
    int c = cnt[b];
    float cf = (float)(c > 0 ? c : 1);
    float g = acc / cf + bl[0];
    out[b] = 1.f / (1.f + __expf(-g));
}

extern "C" void kernel_launch(void* const* d_in, const int* in_sizes, int n_in,
                              void* d_out, int out_size, void* d_ws, size_t ws_size,
                              hipStream_t stream) {
    const float* x = (const float*)d_in[0];
    const int* ei = (const int*)d_in[1];
    const int* batch = (const int*)d_in[2];
    const float* W1 = (const float*)d_in[3];
    const float* aw_s1 = (const float*)d_in[4];
    const float* aw_d1 = (const float*)d_in[5];
    const float* b1 = (const float*)d_in[6];
    const float* W2 = (const float*)d_in[7];
    const float* aw_s2 = (const float*)d_in[8];
    const float* aw_d2 = (const float*)d_in[9];
    const float* b2 = (const float*)d_in[10];
    const float* Wl = (const float*)d_in[11];
    const float* bl = (const float*)d_in[12];
    const int* srcArr = ei;
    const int* dstArr = ei + EE;

    char* w = (char*)d_ws;
    size_t off = 0;
    auto alloc = [&](size_t bytes) -> void* {
        void* p = (void*)(w + off);
        off = (off + bytes + 255) & ~(size_t)255;
        return p;
    };
    // footprint identical to the R9-proven ~71 MB layout
    bf16* bufA = (bf16*)alloc((size_t)NN * 256 * 2);   // h1 [N,256]; later h2 [N,128]
    bf16* bufB = (bf16*)alloc((size_t)NN * 256 * 2);   // x2 [N,256]
    float* alpha1 = (float*)alloc((size_t)ETOT * 4 * 4);  // reused as alpha2
    float* as1 = (float*)alloc((size_t)NN * 4 * 4);
    float* ad1 = (float*)alloc((size_t)NN * 4 * 4);
    float* as2 = (float*)alloc((size_t)NN * 4);
    float* ad2 = (float*)alloc((size_t)NN * 4);
    int* deg = (int*)alloc((size_t)NN * 4);
    int* offs = (int*)alloc((size_t)(NN + 1) * 4);
    int* cur = (int*)alloc((size_t)NN * 4);   // after k_scatter: reused as wt1+wt2
    int* eid = (int*)alloc((size_t)ETOT * 4);
    int* bsum = (int*)alloc((size_t)NBLK * 4);
    int* boff = (int*)alloc((size_t)NBLK * 4);
    float* pooled = (float*)alloc((size_t)BB * 128 * 4);
    int* cnt = (int*)alloc((size_t)BB * 4);
    (void)ws_size;

    // wt1 (64KB) + wt2 (64KB) alias cur's 200KB, used only after k_scatter
    bf16* wt1 = (bf16*)cur;
    bf16* wt2 = (bf16*)cur + 256 * 128;

    k_zeroi<<<NBLK, 256, 0, stream>>>(deg, NN);
    k_zerof<<<(BB * 128 + 255) / 256, 256, 0, stream>>>(pooled, BB * 128);
    k_zeroi<<<(BB + 255) / 256, 256, 0, stream>>>(cnt, BB);

    k_count<<<(ETOT + 255) / 256, 256, 0, stream>>>(dstArr, deg);
    k_scan1<<<NBLK, 256, 0, stream>>>(deg, offs, cur, bsum);
    k_scan2<<<1, 256, 0, stream>>>(bsum, boff, offs);
    k_scan3<<<NBLK, 256, 0, stream>>>(boff, offs, cur);
    k_scatter<<<(ETOT + 255) / 256, 256, 0, stream>>>(dstArr, cur, eid);
    k_cnt<<<NBLK, 256, 0, stream>>>(batch, cnt);

    // cur is dead now -> write transposed bf16 weights into its space
    k_cvtw1<<<128, 256, 0, stream>>>(W1, wt1);
    k_cvtw2<<<128, 256, 0, stream>>>(W2, wt2);

    bf16* h1 = bufA;
    bf16* x2 = bufB;
    k_gemm1<<<(NN + 63) / 64, 256, 0, stream>>>(x, wt1, aw_s1, aw_d1, h1, as1, ad1);
    k_soft1<<<(NN * 4 + 255) / 256, 256, 0, stream>>>(srcArr, offs, eid, as1, ad1, alpha1);
    k_gather1<<<NN, 64, 0, stream>>>(srcArr, offs, eid, h1, alpha1, b1, x2);

    bf16* h2 = bufA;  // h1 dead after gather1
    k_gemm2<<<(NN + 63) / 64, 256, 0, stream>>>(x2, wt2, aw_s2, aw_d2, h2, as2, ad2);

    float* alpha2 = alpha1;  // alpha1 dead after gather1
    k_soft2<<<NBLK, 256, 0, stream>>>(srcArr, offs, eid, as2, ad2, alpha2);
    k_gather2<<<NN, 64, 0, stream>>>(srcArr, offs, eid, h2, alpha2, b2, batch, pooled);

    k_final<<<2, 256, 0, stream>>>(pooled, cnt, Wl, bl, (float*)d_out);
}

// Round 12
// 509.920 us; speedup vs baseline: 1.7585x; 1.0157x over previous
//
#include <hip/hip_runtime.h>
#include <hip/hip_bf16.h>

#define NN 50000
#define EE 800000
#define ETOT 850000
#define BB 512
#define NBLK 196   // ceil(NN/256)

typedef __hip_bfloat16 bf16;
typedef __attribute__((ext_vector_type(8))) __bf16 v8bf;
typedef __attribute__((ext_vector_type(4))) float f32x4;

__device__ __forceinline__ float b2f(bf16 v) { return __bfloat162float(v); }
__device__ __forceinline__ float lo2f(unsigned int u) {
    return __uint_as_float(u << 16);
}
__device__ __forceinline__ float hi2f(unsigned int u) {
    return __uint_as_float(u & 0xffff0000u);
}
__device__ __forceinline__ unsigned short f2bfbits(float f) {
    bf16 h = __float2bfloat16(f);
    return *reinterpret_cast<unsigned short*>(&h);
}

// ---------------- zeroing ----------------
__global__ void k_zeroi(int* __restrict__ p, int n) {
    int i = blockIdx.x * blockDim.x + threadIdx.x;
    if (i < n) p[i] = 0;
}
__global__ void k_zerof(float* __restrict__ p, int n) {
    int i = blockIdx.x * blockDim.x + threadIdx.x;
    if (i < n) p[i] = 0.f;
}

// ---------------- weight transpose+cvt (launched AFTER k_scatter; aliases cur) ----------------
__global__ void k_cvtw1(const float* __restrict__ W1, bf16* __restrict__ wt1) {
    int idx = blockIdx.x * blockDim.x + threadIdx.x;
    if (idx >= 256 * 128) return;
    int c = idx >> 7, k = idx & 127;
    wt1[idx] = __float2bfloat16(W1[k * 256 + c]);
}
__global__ void k_cvtw2(const float* __restrict__ W2, bf16* __restrict__ wt2) {
    int idx = blockIdx.x * blockDim.x + threadIdx.x;
    if (idx >= 128 * 256) return;
    int c = idx >> 8, k = idx & 255;
    wt2[idx] = __float2bfloat16(W2[k * 128 + c]);
}

// ---------------- CSR build ----------------
__global__ void k_count(const int* __restrict__ dstArr, int* __restrict__ deg) {
    int e = blockIdx.x * blockDim.x + threadIdx.x;
    if (e >= ETOT) return;
    int d = (e < EE) ? dstArr[e] : (e - EE);
    d = min(max(d, 0), NN - 1);
    atomicAdd(&deg[d], 1);
}

__global__ void k_scan1(const int* __restrict__ deg, int* __restrict__ offs,
                        int* __restrict__ cur, int* __restrict__ bsum) {
    __shared__ int s[256];
    int t = threadIdx.x;
    int i = blockIdx.x * 256 + t;
    int v = (i < NN) ? deg[i] : 0;
    s[t] = v;
    __syncthreads();
    for (int o = 1; o < 256; o <<= 1) {
        int tv = (t >= o) ? s[t - o] : 0;
        __syncthreads();
        s[t] += tv;
        __syncthreads();
    }
    int excl = s[t] - v;
    if (i < NN) { offs[i] = excl; cur[i] = excl; }
    if (t == 255) bsum[blockIdx.x] = s[255];
}

__global__ void k_scan2(const int* __restrict__ bsum, int* __restrict__ boff,
                        int* __restrict__ offs) {
    __shared__ int s[256];
    int t = threadIdx.x;
    int v = (t < NBLK) ? bsum[t] : 0;
    s[t] = v;
    __syncthreads();
    for (int o = 1; o < 256; o <<= 1) {
        int tv = (t >= o) ? s[t - o] : 0;
        __syncthreads();
        s[t] += tv;
        __syncthreads();
    }
    if (t < NBLK) boff[t] = s[t] - v;
    if (t == 0) offs[NN] = ETOT;
}

__global__ void k_scan3(const int* __restrict__ boff, int* __restrict__ offs,
                        int* __restrict__ cur) {
    int i = blockIdx.x * 256 + threadIdx.x;
    if (i < NN) {
        int b = boff[blockIdx.x];
        offs[i] += b;
        cur[i] += b;
    }
}

__global__ void k_scatter(const int* __restrict__ dstArr, int* __restrict__ cur,
                          int* __restrict__ eid) {
    int e = blockIdx.x * blockDim.x + threadIdx.x;
    if (e >= ETOT) return;
    int d = (e < EE) ? dstArr[e] : (e - EE);
    d = min(max(d, 0), NN - 1);
    int p = atomicAdd(&cur[d], 1);
    if (p >= 0 && p < ETOT) eid[p] = e;
}

// ---------------- Layer 1 GEMM via MFMA: 32 nodes/block, 8 acc tiles/wave ----------------
// wave wv: rows (wv&1)*16, cols (wv>>1)*128. Grid 1563.
__global__ __launch_bounds__(256, 2)
void k_gemm1(const float* __restrict__ x, const bf16* __restrict__ wt1,
             const float* __restrict__ aw_s, const float* __restrict__ aw_d,
             bf16* __restrict__ h1, float* __restrict__ as1,
             float* __restrict__ ad1) {
    int n0 = blockIdx.x * 32;
    int t = threadIdx.x;
    __shared__ bf16 xs[32 * 136];   // 8.7 KB
    for (int i = 0; i < 4; i++) {
        int idx = t + 256 * i;          // 0..1023
        int r = idx >> 5, c4 = idx & 31;
        float4 v = make_float4(0.f, 0.f, 0.f, 0.f);
        if (n0 + r < NN) v = *(const float4*)(x + (size_t)(n0 + r) * 128 + c4 * 4);
        ushort4 o;
        o.x = f2bfbits(v.x); o.y = f2bfbits(v.y);
        o.z = f2bfbits(v.z); o.w = f2bfbits(v.w);
        *(ushort4*)(&xs[r * 136 + c4 * 4]) = o;
    }
    __syncthreads();

    int wv = t >> 6, lane = t & 63;
    int q = lane >> 4, r16 = lane & 15;
    int rowBase = (wv & 1) * 16;
    int colBase = (wv >> 1) * 128;

    f32x4 acc[8];
#pragma unroll
    for (int ct = 0; ct < 8; ct++) acc[ct] = (f32x4){0.f, 0.f, 0.f, 0.f};

#pragma unroll
    for (int kt = 0; kt < 4; kt++) {
        v8bf va = *(const v8bf*)(&xs[(rowBase + r16) * 136 + kt * 32 + q * 8]);
#pragma unroll
        for (int ct = 0; ct < 8; ct++) {
            v8bf vb = *(const v8bf*)(wt1 + (size_t)(colBase + ct * 16 + r16) * 128 + kt * 32 + q * 8);
            acc[ct] = __builtin_amdgcn_mfma_f32_16x16x32_bf16(va, vb, acc[ct], 0, 0, 0);
        }
    }

    // hoisted attention-weight loads (16 scalars/thread, once)
    float wsv[8], wdv[8];
#pragma unroll
    for (int ct = 0; ct < 8; ct++) {
        int col = colBase + ct * 16 + r16;
        wsv[ct] = aw_s[col];
        wdv[ct] = aw_d[col];
    }

    float ps[4][2], pd[4][2];
#pragma unroll
    for (int reg = 0; reg < 4; reg++) {
        ps[reg][0] = 0.f; ps[reg][1] = 0.f;
        pd[reg][0] = 0.f; pd[reg][1] = 0.f;
    }

#pragma unroll
    for (int reg = 0; reg < 4; reg++) {
        int node = n0 + rowBase + q * 4 + reg;
        bool ok = node < NN;
#pragma unroll
        for (int ct = 0; ct < 8; ct++) {
            float v = acc[ct][reg];
            if (ok) h1[(size_t)node * 256 + colBase + ct * 16 + r16] = __float2bfloat16(v);
            ps[reg][ct >> 2] += v * wsv[ct];
            pd[reg][ct >> 2] += v * wdv[ct];
        }
    }

#pragma unroll
    for (int reg = 0; reg < 4; reg++) {
        int node = n0 + rowBase + q * 4 + reg;
        bool ok = node < NN;
#pragma unroll
        for (int lh = 0; lh < 2; lh++) {
            float a = ps[reg][lh], b = pd[reg][lh];
            for (int mask = 1; mask <= 8; mask <<= 1) {
                a += __shfl_xor(a, mask);
                b += __shfl_xor(b, mask);
            }
            if (r16 == 0 && ok) {
                int head = (wv >> 1) * 2 + lh;
                as1[node * 4 + head] = a;
                ad1[node * 4 + head] = b;
            }
        }
    }
}

// ---------------- Layer 1 softmax weights ----------------
__global__ void k_soft1(const int* __restrict__ srcArr, const int* __restrict__ offs,
                        const int* __restrict__ eid, const float* __restrict__ as1,
                        const float* __restrict__ ad1, float* __restrict__ alpha1) {
    int gid = blockIdx.x * blockDim.x + threadIdx.x;
    int n = gid >> 2, h = gid & 3;
    if (n >= NN) return;
    int beg = offs[n], end = offs[n + 1];
    beg = min(max(beg, 0), ETOT);
    end = min(max(end, beg), ETOT);
    float adh = ad1[n * 4 + h];
    float m = -1e30f;
    for (int p = beg; p < end; p++) {
        int e = eid[p];
        e = min(max(e, 0), ETOT - 1);
        int s = (e < EE) ? srcArr[e] : (e - EE);
        s = min(max(s, 0), NN - 1);
        float ev = as1[s * 4 + h] + adh;
        ev = ev > 0.f ? ev : 0.2f * ev;        // leaky_relu(0.2)
        alpha1[(size_t)p * 4 + h] = ev;
        m = fmaxf(m, ev);
    }
    float sum = 0.f;
    for (int p = beg; p < end; p++) {
        float wgt = __expf(alpha1[(size_t)p * 4 + h] - m);
        alpha1[(size_t)p * 4 + h] = wgt;
        sum += wgt;
    }
    float inv = 1.f / fmaxf(sum, 1e-30f);
    for (int p = beg; p < end; p++)
        alpha1[(size_t)p * 4 + h] *= inv;
}

// ---------------- Layer 1 gather: one wave per node, 4 cols/thread ----------------
__global__ void k_gather1(const int* __restrict__ srcArr, const int* __restrict__ offs,
                          const int* __restrict__ eid, const bf16* __restrict__ h1,
                          const float* __restrict__ alpha1, const float* __restrict__ b1,
                          bf16* __restrict__ x2) {
    int n = blockIdx.x;
    int t = threadIdx.x;        // 0..63
    int h = t >> 4;             // head of cols t*4..t*4+3
    int beg = offs[n], end = offs[n + 1];
    beg = min(max(beg, 0), ETOT);
    end = min(max(end, beg), ETOT);
    float a0 = 0.f, a1 = 0.f, a2 = 0.f, a3 = 0.f;
    __shared__ int ls[64];
    __shared__ float la[64 * 4];
    const unsigned short* h1u = (const unsigned short*)h1;
    for (int cb = beg; cb < end; cb += 64) {
        int cnt = min(64, end - cb);
        __syncthreads();
        if (t < cnt) {
            int e = eid[cb + t];
            e = min(max(e, 0), ETOT - 1);
            int s = (e < EE) ? srcArr[e] : (e - EE);
            ls[t] = min(max(s, 0), NN - 1);
            *(float4*)&la[t * 4] = *(const float4*)&alpha1[(size_t)(cb + t) * 4];
        }
        __syncthreads();
        for (int j = 0; j < cnt; j++) {
            int s = ls[j];
            float a = la[j * 4 + h];
            uint2 u = *(const uint2*)(h1u + (size_t)s * 256 + t * 4);
            a0 = fmaf(a, lo2f(u.x), a0);
            a1 = fmaf(a, hi2f(u.x), a1);
            a2 = fmaf(a, lo2f(u.y), a2);
            a3 = fmaf(a, hi2f(u.y), a3);
        }
    }
    int c = t * 4;
    float r0 = a0 + b1[c + 0];
    float r1 = a1 + b1[c + 1];
    float r2 = a2 + b1[c + 2];
    float r3 = a3 + b1[c + 3];
    r0 = r0 > 0.f ? r0 : (__expf(r0) - 1.f);
    r1 = r1 > 0.f ? r1 : (__expf(r1) - 1.f);
    r2 = r2 > 0.f ? r2 : (__expf(r2) - 1.f);
    r3 = r3 > 0.f ? r3 : (__expf(r3) - 1.f);
    bf16* xr = x2 + (size_t)n * 256 + c;
    xr[0] = __float2bfloat16(r0);
    xr[1] = __float2bfloat16(r1);
    xr[2] = __float2bfloat16(r2);
    xr[3] = __float2bfloat16(r3);
}

// ---------------- Layer 2 GEMM via MFMA (unchanged from R11) ----------------
__global__ void k_gemm2(const bf16* __restrict__ x2, const bf16* __restrict__ wt2,
                        const float* __restrict__ aw_s, const float* __restrict__ aw_d,
                        bf16* __restrict__ h2, float* __restrict__ as2,
                        float* __restrict__ ad2) {
    int n0 = blockIdx.x * 64;
    int t = threadIdx.x;
    __shared__ bf16 xs[64 * 264];   // 33 KB
    for (int i = 0; i < 8; i++) {
        int idx = t + 256 * i;          // 0..2047
        int r = idx >> 5, c8 = idx & 31;
        uint4 v;
        if (n0 + r < NN) v = *(const uint4*)(x2 + (size_t)(n0 + r) * 256 + c8 * 8);
        else             v = make_uint4(0, 0, 0, 0);
        *(uint4*)(&xs[r * 264 + c8 * 8]) = v;
    }
    __syncthreads();

    int wv = t >> 6, lane = t & 63;
    int q = lane >> 4, r16 = lane & 15;
    int nw = wv * 16;

    f32x4 acc[8];
#pragma unroll
    for (int ct = 0; ct < 8; ct++) acc[ct] = (f32x4){0.f, 0.f, 0.f, 0.f};

#pragma unroll
    for (int kt = 0; kt < 8; kt++) {
        v8bf va = *(const v8bf*)(&xs[(nw + r16) * 264 + kt * 32 + q * 8]);
#pragma unroll
        for (int ct = 0; ct < 8; ct++) {
            v8bf vb = *(const v8bf*)(wt2 + (size_t)(ct * 16 + r16) * 256 + kt * 32 + q * 8);
            acc[ct] = __builtin_amdgcn_mfma_f32_16x16x32_bf16(va, vb, acc[ct], 0, 0, 0);
        }
    }

#pragma unroll
    for (int reg = 0; reg < 4; reg++) {
        int node = n0 + nw + q * 4 + reg;
        bool ok = node < NN;
        float ps = 0.f, pd = 0.f;
#pragma unroll
        for (int ct = 0; ct < 8; ct++) {
            int col = ct * 16 + r16;
            float v = acc[ct][reg];
            if (ok) h2[(size_t)node * 128 + col] = __float2bfloat16(v);
            ps += v * aw_s[col];
            pd += v * aw_d[col];
        }
        for (int mask = 1; mask <= 8; mask <<= 1) {
            ps += __shfl_xor(ps, mask);
            pd += __shfl_xor(pd, mask);
        }
        if (r16 == 0 && ok) {
            as2[node] = ps;
            ad2[node] = pd;
        }
    }
}

// ---------------- Layer 2 softmax weights ----------------
__global__ void k_soft2(const int* __restrict__ srcArr, const int* __restrict__ offs,
                        const int* __restrict__ eid, const float* __restrict__ as2,
                        const float* __restrict__ ad2, float* __restrict__ alpha2) {
    int n = blockIdx.x * blockDim.x + threadIdx.x;
    if (n >= NN) return;
    int beg = offs[n], end = offs[n + 1];
    beg = min(max(beg, 0), ETOT);
    end = min(max(end, beg), ETOT);
    float adn = ad2[n];
    float m = -1e30f;
    for (int p = beg; p < end; p++) {
        int e = eid[p];
        e = min(max(e, 0), ETOT - 1);
        int s = (e < EE) ? srcArr[e] : (e - EE);
        s = min(max(s, 0), NN - 1);
        float ev = as2[s] + adn;
        ev = ev > 0.f ? ev : 0.2f * ev;
        alpha2[p] = ev;
        m = fmaxf(m, ev);
    }
    float sum = 0.f;
    for (int p = beg; p < end; p++) {
        float wgt = __expf(alpha2[p] - m);
        alpha2[p] = wgt;
        sum += wgt;
    }
    float inv = 1.f / fmaxf(sum, 1e-30f);
    for (int p = beg; p < end; p++) alpha2[p] *= inv;
}

// ---------------- Layer 2 gather + fused mean-pool: one wave per node ----------------
__global__ void k_gather2(const int* __restrict__ srcArr, const int* __restrict__ offs,
                          const int* __restrict__ eid, const bf16* __restrict__ h2,
                          const float* __restrict__ alpha2, const float* __restrict__ b2,
                          const int* __restrict__ batch, float* __restrict__ pooled) {
    int n = blockIdx.x;
    int t = threadIdx.x;        // 0..63
    int beg = offs[n], end = offs[n + 1];
    beg = min(max(beg, 0), ETOT);
    end = min(max(end, beg), ETOT);
    float a0 = 0.f, a1 = 0.f;
    __shared__ int ls[64];
    __shared__ float la[64];
    const unsigned short* h2u = (const unsigned short*)h2;
    for (int cb = beg; cb < end; cb += 64) {
        int cnt = min(64, end - cb);
        __syncthreads();
        if (t < cnt) {
            int e = eid[cb + t];
            e = min(max(e, 0), ETOT - 1);
            int s = (e < EE) ? srcArr[e] : (e - EE);
            ls[t] = min(max(s, 0), NN - 1);
            la[t] = alpha2[cb + t];
        }
        __syncthreads();
        for (int j = 0; j < cnt; j++) {
            int s = ls[j];
            float a = la[j];
            unsigned int u = *(const unsigned int*)(h2u + (size_t)s * 128 + t * 2);
            a0 = fmaf(a, lo2f(u), a0);
            a1 = fmaf(a, hi2f(u), a1);
        }
    }
    int c = t * 2;
    float r0 = a0 + b2[c + 0];
    float r1 = a1 + b2[c + 1];
    r0 = r0 > 0.f ? r0 : (__expf(r0) - 1.f);
    r1 = r1 > 0.f ? r1 : (__expf(r1) - 1.f);
    int b = batch[n];
    b = min(max(b, 0), BB - 1);
    atomicAdd(&pooled[b * 128 + c + 0], r0);
    atomicAdd(&pooled[b * 128 + c + 1], r1);
}

// ---------------- per-graph node counts ----------------
__global__ void k_cnt(const int* __restrict__ batch, int* __restrict__ cnt) {
    int n = blockIdx.x * blockDim.x + threadIdx.x;
    if (n >= NN) return;
    int b = batch[n];
    b = min(max(b, 0), BB - 1);
    atomicAdd(&cnt[b], 1);
}

// ---------------- final linear + sigmoid (f32 output) ----------------
__global__ void k_final(const float* __restrict__ pooled, const int* __restrict__ cnt,
                        const float* __restrict__ Wl, const float* __restrict__ bl,
                        float* __restrict__ out) {
    int b = blockIdx.x * blockDim.x + threadIdx.x;
    if (b >= BB) return;
    float acc = 0.f;
    for (int k = 0; k < 128; k++) acc += pooled[b * 128 + k] * Wl[k];
    int c = cnt[b];
    float cf = (float)(c > 0 ? c : 1);
    float g = acc / cf + bl[0];
    out[b] = 1.f / (1.f + __expf(-g));
}

extern "C" void kernel_launch(void* const* d_in, const int* in_sizes, int n_in,
                              void* d_out, int out_size, void* d_ws, size_t ws_size,
                              hipStream_t stream) {
    const float* x = (const float*)d_in[0];
    const int* ei = (const int*)d_in[1];
    const int* batch = (const int*)d_in[2];
    const float* W1 = (const float*)d_in[3];
    const float* aw_s1 = (const float*)d_in[4];
    const float* aw_d1 = (const float*)d_in[5];
    const float* b1 = (const float*)d_in[6];
    const float* W2 = (const float*)d_in[7];
    const float* aw_s2 = (const float*)d_in[8];
    const float* aw_d2 = (const float*)d_in[9];
    const float* b2 = (const float*)d_in[10];
    const float* Wl = (const float*)d_in[11];
    const float* bl = (const float*)d_in[12];
    const int* srcArr = ei;
    const int* dstArr = ei + EE;

    char* w = (char*)d_ws;
    size_t off = 0;
    auto alloc = [&](size_t bytes) -> void* {
        void* p = (void*)(w + off);
        off = (off + bytes + 255) & ~(size_t)255;
        return p;
    };
    // footprint identical to the R9/R11-proven ~71 MB layout
    bf16* bufA = (bf16*)alloc((size_t)NN * 256 * 2);   // h1 [N,256]; later h2 [N,128]
    bf16* bufB = (bf16*)alloc((size_t)NN * 256 * 2);   // x2 [N,256]
    float* alpha1 = (float*)alloc((size_t)ETOT * 4 * 4);  // reused as alpha2
    float* as1 = (float*)alloc((size_t)NN * 4 * 4);
    float* ad1 = (float*)alloc((size_t)NN * 4 * 4);
    float* as2 = (float*)alloc((size_t)NN * 4);
    float* ad2 = (float*)alloc((size_t)NN * 4);
    int* deg = (int*)alloc((size_t)NN * 4);
    int* offs = (int*)alloc((size_t)(NN + 1) * 4);
    int* cur = (int*)alloc((size_t)NN * 4);   // after k_scatter: reused as wt1+wt2
    int* eid = (int*)alloc((size_t)ETOT * 4);
    int* bsum = (int*)alloc((size_t)NBLK * 4);
    int* boff = (int*)alloc((size_t)NBLK * 4);
    float* pooled = (float*)alloc((size_t)BB * 128 * 4);
    int* cnt = (int*)alloc((size_t)BB * 4);
    (void)ws_size;

    bf16* wt1 = (bf16*)cur;
    bf16* wt2 = (bf16*)cur + 256 * 128;

    k_zeroi<<<NBLK, 256, 0, stream>>>(deg, NN);
    k_zerof<<<(BB * 128 + 255) / 256, 256, 0, stream>>>(pooled, BB * 128);
    k_zeroi<<<(BB + 255) / 256, 256, 0, stream>>>(cnt, BB);

    k_count<<<(ETOT + 255) / 256, 256, 0, stream>>>(dstArr, deg);
    k_scan1<<<NBLK, 256, 0, stream>>>(deg, offs, cur, bsum);
    k_scan2<<<1, 256, 0, stream>>>(bsum, boff, offs);
    k_scan3<<<NBLK, 256, 0, stream>>>(boff, offs, cur);
    k_scatter<<<(ETOT + 255) / 256, 256, 0, stream>>>(dstArr, cur, eid);
    k_cnt<<<NBLK, 256, 0, stream>>>(batch, cnt);

    // cur dead -> transposed bf16 weights live in its space
    k_cvtw1<<<128, 256, 0, stream>>>(W1, wt1);
    k_cvtw2<<<128, 256, 0, stream>>>(W2, wt2);

    bf16* h1 = bufA;
    bf16* x2 = bufB;
    k_gemm1<<<(NN + 31) / 32, 256, 0, stream>>>(x, wt1, aw_s1, aw_d1, h1, as1, ad1);
    k_soft1<<<(NN * 4 + 255) / 256, 256, 0, stream>>>(srcArr, offs, eid, as1, ad1, alpha1);
    k_gather1<<<NN, 64, 0, stream>>>(srcArr, offs, eid, h1, alpha1, b1, x2);

    bf16* h2 = bufA;  // h1 dead after gather1
    k_gemm2<<<(NN + 63) / 64, 256, 0, stream>>>(x2, wt2, aw_s2, aw_d2, h2, as2, ad2);

    float* alpha2 = alpha1;  // alpha1 dead after gather1
    k_soft2<<<NBLK, 256, 0, stream>>>(srcArr, offs, eid, as2, ad2, alpha2);
    k_gather2<<<NN, 64, 0, stream>>>(srcArr, offs, eid, h2, alpha2, b2, batch, pooled);

    k_final<<<2, 256, 0, stream>>>(pooled, cnt, Wl, bl, (float*)d_out);
}

// Round 13
// 485.160 us; speedup vs baseline: 1.8483x; 1.0510x over previous
//
#include <hip/hip_runtime.h>
#include <hip/hip_bf16.h>

#define NN 50000
#define EE 800000
#define ETOT 850000
#define BB 512
#define NBLK 196   // ceil(NN/256)

typedef __hip_bfloat16 bf16;
typedef __attribute__((ext_vector_type(8))) __bf16 v8bf;
typedef __attribute__((ext_vector_type(4))) float f32x4;

__device__ __forceinline__ float b2f(bf16 v) { return __bfloat162float(v); }
__device__ __forceinline__ float lo2f(unsigned int u) {
    return __uint_as_float(u << 16);
}
__device__ __forceinline__ float hi2f(unsigned int u) {
    return __uint_as_float(u & 0xffff0000u);
}
__device__ __forceinline__ unsigned short f2bfbits(float f) {
    bf16 h = __float2bfloat16(f);
    return *reinterpret_cast<unsigned short*>(&h);
}

// ---------------- fused init: zero deg/pooled/cnt ----------------
__global__ void k_init(int* __restrict__ deg, float* __restrict__ pooled,
                       int* __restrict__ cnt) {
    int i = blockIdx.x * blockDim.x + threadIdx.x;
    if (i < NN) deg[i] = 0;
    if (i < BB * 128) pooled[i] = 0.f;
    if (i < BB) cnt[i] = 0;
}

// ---------------- fused weight transpose+cvt (aliases cur, after k_scatter) ----------------
__global__ void k_cvtw(const float* __restrict__ W1, const float* __restrict__ W2,
                       bf16* __restrict__ wt1, bf16* __restrict__ wt2) {
    int idx = blockIdx.x * blockDim.x + threadIdx.x;
    if (idx < 256 * 128) {
        int c = idx >> 7, k = idx & 127;
        wt1[idx] = __float2bfloat16(W1[k * 256 + c]);
    } else {
        int j = idx - 256 * 128;      // < 128*256
        int c = j >> 8, k = j & 255;
        wt2[j] = __float2bfloat16(W2[k * 128 + c]);
    }
}

// ---------------- CSR build ----------------
__global__ void k_count(const int* __restrict__ dstArr, int* __restrict__ deg) {
    int e = blockIdx.x * blockDim.x + threadIdx.x;
    if (e >= ETOT) return;
    int d = (e < EE) ? dstArr[e] : (e - EE);
    d = min(max(d, 0), NN - 1);
    atomicAdd(&deg[d], 1);
}

__global__ void k_scan1(const int* __restrict__ deg, int* __restrict__ offs,
                        int* __restrict__ cur, int* __restrict__ bsum) {
    __shared__ int s[256];
    int t = threadIdx.x;
    int i = blockIdx.x * 256 + t;
    int v = (i < NN) ? deg[i] : 0;
    s[t] = v;
    __syncthreads();
    for (int o = 1; o < 256; o <<= 1) {
        int tv = (t >= o) ? s[t - o] : 0;
        __syncthreads();
        s[t] += tv;
        __syncthreads();
    }
    int excl = s[t] - v;
    if (i < NN) { offs[i] = excl; cur[i] = excl; }
    if (t == 255) bsum[blockIdx.x] = s[255];
}

__global__ void k_scan2(const int* __restrict__ bsum, int* __restrict__ boff,
                        int* __restrict__ offs) {
    __shared__ int s[256];
    int t = threadIdx.x;
    int v = (t < NBLK) ? bsum[t] : 0;
    s[t] = v;
    __syncthreads();
    for (int o = 1; o < 256; o <<= 1) {
        int tv = (t >= o) ? s[t - o] : 0;
        __syncthreads();
        s[t] += tv;
        __syncthreads();
    }
    if (t < NBLK) boff[t] = s[t] - v;
    if (t == 0) offs[NN] = ETOT;
}

// scan3 + per-graph node count fused
__global__ void k_scan3(const int* __restrict__ boff, int* __restrict__ offs,
                        int* __restrict__ cur, const int* __restrict__ batch,
                        int* __restrict__ cnt) {
    int i = blockIdx.x * 256 + threadIdx.x;
    if (i < NN) {
        int b = boff[blockIdx.x];
        offs[i] += b;
        cur[i] += b;
        int g = batch[i];
        g = min(max(g, 0), BB - 1);
        atomicAdd(&cnt[g], 1);
    }
}

__global__ void k_scatter(const int* __restrict__ dstArr, int* __restrict__ cur,
                          int* __restrict__ eid) {
    int e = blockIdx.x * blockDim.x + threadIdx.x;
    if (e >= ETOT) return;
    int d = (e < EE) ? dstArr[e] : (e - EE);
    d = min(max(d, 0), NN - 1);
    int p = atomicAdd(&cur[d], 1);
    if (p >= 0 && p < ETOT) eid[p] = e;
}

// ---------------- Layer 1 GEMM via MFMA: 32 nodes/block (proven R12) ----------------
__global__ __launch_bounds__(256, 2)
void k_gemm1(const float* __restrict__ x, const bf16* __restrict__ wt1,
             const float* __restrict__ aw_s, const float* __restrict__ aw_d,
             bf16* __restrict__ h1, float* __restrict__ as1,
             float* __restrict__ ad1) {
    int n0 = blockIdx.x * 32;
    int t = threadIdx.x;
    __shared__ bf16 xs[32 * 136];
    for (int i = 0; i < 4; i++) {
        int idx = t + 256 * i;
        int r = idx >> 5, c4 = idx & 31;
        float4 v = make_float4(0.f, 0.f, 0.f, 0.f);
        if (n0 + r < NN) v = *(const float4*)(x + (size_t)(n0 + r) * 128 + c4 * 4);
        ushort4 o;
        o.x = f2bfbits(v.x); o.y = f2bfbits(v.y);
        o.z = f2bfbits(v.z); o.w = f2bfbits(v.w);
        *(ushort4*)(&xs[r * 136 + c4 * 4]) = o;
    }
    __syncthreads();

    int wv = t >> 6, lane = t & 63;
    int q = lane >> 4, r16 = lane & 15;
    int rowBase = (wv & 1) * 16;
    int colBase = (wv >> 1) * 128;

    f32x4 acc[8];
#pragma unroll
    for (int ct = 0; ct < 8; ct++) acc[ct] = (f32x4){0.f, 0.f, 0.f, 0.f};

#pragma unroll
    for (int kt = 0; kt < 4; kt++) {
        v8bf va = *(const v8bf*)(&xs[(rowBase + r16) * 136 + kt * 32 + q * 8]);
#pragma unroll
        for (int ct = 0; ct < 8; ct++) {
            v8bf vb = *(const v8bf*)(wt1 + (size_t)(colBase + ct * 16 + r16) * 128 + kt * 32 + q * 8);
            acc[ct] = __builtin_amdgcn_mfma_f32_16x16x32_bf16(va, vb, acc[ct], 0, 0, 0);
        }
    }

    float wsv[8], wdv[8];
#pragma unroll
    for (int ct = 0; ct < 8; ct++) {
        int col = colBase + ct * 16 + r16;
        wsv[ct] = aw_s[col];
        wdv[ct] = aw_d[col];
    }

    float ps[4][2], pd[4][2];
#pragma unroll
    for (int reg = 0; reg < 4; reg++) {
        ps[reg][0] = 0.f; ps[reg][1] = 0.f;
        pd[reg][0] = 0.f; pd[reg][1] = 0.f;
    }

#pragma unroll
    for (int reg = 0; reg < 4; reg++) {
        int node = n0 + rowBase + q * 4 + reg;
        bool ok = node < NN;
#pragma unroll
        for (int ct = 0; ct < 8; ct++) {
            float v = acc[ct][reg];
            if (ok) h1[(size_t)node * 256 + colBase + ct * 16 + r16] = __float2bfloat16(v);
            ps[reg][ct >> 2] += v * wsv[ct];
            pd[reg][ct >> 2] += v * wdv[ct];
        }
    }

#pragma unroll
    for (int reg = 0; reg < 4; reg++) {
        int node = n0 + rowBase + q * 4 + reg;
        bool ok = node < NN;
#pragma unroll
        for (int lh = 0; lh < 2; lh++) {
            float a = ps[reg][lh], b = pd[reg][lh];
            for (int mask = 1; mask <= 8; mask <<= 1) {
                a += __shfl_xor(a, mask);
                b += __shfl_xor(b, mask);
            }
            if (r16 == 0 && ok) {
                int head = (wv >> 1) * 2 + lh;
                as1[node * 4 + head] = a;
                ad1[node * 4 + head] = b;
            }
        }
    }
}

// ---------------- Layer 1 softmax: one thread per node, UNNORMALIZED exp ----------------
__global__ void k_soft1(const int* __restrict__ srcArr, const int* __restrict__ offs,
                        const int* __restrict__ eid, const float* __restrict__ as1,
                        const float* __restrict__ ad1, float* __restrict__ alpha1) {
    int n = blockIdx.x * blockDim.x + threadIdx.x;
    if (n >= NN) return;
    int beg = offs[n], end = offs[n + 1];
    beg = min(max(beg, 0), ETOT);
    end = min(max(end, beg), ETOT);
    float4 ad = *(const float4*)&ad1[n * 4];
    for (int p = beg; p < end; p++) {
        int e = eid[p];
        e = min(max(e, 0), ETOT - 1);
        int s = (e < EE) ? srcArr[e] : (e - EE);
        s = min(max(s, 0), NN - 1);
        float4 as = *(const float4*)&as1[s * 4];
        float4 w;
        float ev;
        ev = as.x + ad.x; ev = ev > 0.f ? ev : 0.2f * ev; w.x = __expf(fminf(ev, 80.f));
        ev = as.y + ad.y; ev = ev > 0.f ? ev : 0.2f * ev; w.y = __expf(fminf(ev, 80.f));
        ev = as.z + ad.z; ev = ev > 0.f ? ev : 0.2f * ev; w.z = __expf(fminf(ev, 80.f));
        ev = as.w + ad.w; ev = ev > 0.f ? ev : 0.2f * ev; w.w = __expf(fminf(ev, 80.f));
        *(float4*)&alpha1[(size_t)p * 4] = w;
    }
}

// ---------------- Layer 1 gather: one wave per node; divides by ssum ----------------
__global__ void k_gather1(const int* __restrict__ srcArr, const int* __restrict__ offs,
                          const int* __restrict__ eid, const bf16* __restrict__ h1,
                          const float* __restrict__ alpha1, const float* __restrict__ b1,
                          bf16* __restrict__ x2) {
    int n = blockIdx.x;
    int t = threadIdx.x;        // 0..63
    int h = t >> 4;             // head of cols t*4..t*4+3
    int beg = offs[n], end = offs[n + 1];
    beg = min(max(beg, 0), ETOT);
    end = min(max(end, beg), ETOT);
    float a0 = 0.f, a1 = 0.f, a2 = 0.f, a3 = 0.f, ssum = 0.f;
    __shared__ int ls[64];
    __shared__ float la[64 * 4];
    const unsigned short* h1u = (const unsigned short*)h1;
    for (int cb = beg; cb < end; cb += 64) {
        int cnt = min(64, end - cb);
        __syncthreads();
        if (t < cnt) {
            int e = eid[cb + t];
            e = min(max(e, 0), ETOT - 1);
            int s = (e < EE) ? srcArr[e] : (e - EE);
            ls[t] = min(max(s, 0), NN - 1);
            *(float4*)&la[t * 4] = *(const float4*)&alpha1[(size_t)(cb + t) * 4];
        }
        __syncthreads();
        int j = 0;
        for (; j + 1 < cnt; j += 2) {
            int s0 = ls[j], s1 = ls[j + 1];
            float A0 = la[j * 4 + h], A1 = la[j * 4 + 4 + h];
            uint2 u0 = *(const uint2*)(h1u + (size_t)s0 * 256 + t * 4);
            uint2 u1 = *(const uint2*)(h1u + (size_t)s1 * 256 + t * 4);
            ssum += A0 + A1;
            a0 = fmaf(A0, lo2f(u0.x), a0); a0 = fmaf(A1, lo2f(u1.x), a0);
            a1 = fmaf(A0, hi2f(u0.x), a1); a1 = fmaf(A1, hi2f(u1.x), a1);
            a2 = fmaf(A0, lo2f(u0.y), a2); a2 = fmaf(A1, lo2f(u1.y), a2);
            a3 = fmaf(A0, hi2f(u0.y), a3); a3 = fmaf(A1, hi2f(u1.y), a3);
        }
        if (j < cnt) {
            int s0 = ls[j];
            float A0 = la[j * 4 + h];
            uint2 u0 = *(const uint2*)(h1u + (size_t)s0 * 256 + t * 4);
            ssum += A0;
            a0 = fmaf(A0, lo2f(u0.x), a0);
            a1 = fmaf(A0, hi2f(u0.x), a1);
            a2 = fmaf(A0, lo2f(u0.y), a2);
            a3 = fmaf(A0, hi2f(u0.y), a3);
        }
    }
    float inv = 1.f / fmaxf(ssum, 1e-35f);
    int c = t * 4;
    float r0 = a0 * inv + b1[c + 0];
    float r1 = a1 * inv + b1[c + 1];
    float r2 = a2 * inv + b1[c + 2];
    float r3 = a3 * inv + b1[c + 3];
    r0 = r0 > 0.f ? r0 : (__expf(r0) - 1.f);
    r1 = r1 > 0.f ? r1 : (__expf(r1) - 1.f);
    r2 = r2 > 0.f ? r2 : (__expf(r2) - 1.f);
    r3 = r3 > 0.f ? r3 : (__expf(r3) - 1.f);
    bf16* xr = x2 + (size_t)n * 256 + c;
    xr[0] = __float2bfloat16(r0);
    xr[1] = __float2bfloat16(r1);
    xr[2] = __float2bfloat16(r2);
    xr[3] = __float2bfloat16(r3);
}

// ---------------- Layer 2 GEMM via MFMA (epilogue hoisted) ----------------
__global__ void k_gemm2(const bf16* __restrict__ x2, const bf16* __restrict__ wt2,
                        const float* __restrict__ aw_s, const float* __restrict__ aw_d,
                        bf16* __restrict__ h2, float* __restrict__ as2,
                        float* __restrict__ ad2) {
    int n0 = blockIdx.x * 64;
    int t = threadIdx.x;
    __shared__ bf16 xs[64 * 264];
    for (int i = 0; i < 8; i++) {
        int idx = t + 256 * i;
        int r = idx >> 5, c8 = idx & 31;
        uint4 v;
        if (n0 + r < NN) v = *(const uint4*)(x2 + (size_t)(n0 + r) * 256 + c8 * 8);
        else             v = make_uint4(0, 0, 0, 0);
        *(uint4*)(&xs[r * 264 + c8 * 8]) = v;
    }
    __syncthreads();

    int wv = t >> 6, lane = t & 63;
    int q = lane >> 4, r16 = lane & 15;
    int nw = wv * 16;

    f32x4 acc[8];
#pragma unroll
    for (int ct = 0; ct < 8; ct++) acc[ct] = (f32x4){0.f, 0.f, 0.f, 0.f};

#pragma unroll
    for (int kt = 0; kt < 8; kt++) {
        v8bf va = *(const v8bf*)(&xs[(nw + r16) * 264 + kt * 32 + q * 8]);
#pragma unroll
        for (int ct = 0; ct < 8; ct++) {
            v8bf vb = *(const v8bf*)(wt2 + (size_t)(ct * 16 + r16) * 256 + kt * 32 + q * 8);
            acc[ct] = __builtin_amdgcn_mfma_f32_16x16x32_bf16(va, vb, acc[ct], 0, 0, 0);
        }
    }

    float wsv[8], wdv[8];
#pragma unroll
    for (int ct = 0; ct < 8; ct++) {
        int col = ct * 16 + r16;
        wsv[ct] = aw_s[col];
        wdv[ct] = aw_d[col];
    }

#pragma unroll
    for (int reg = 0; reg < 4; reg++) {
        int node = n0 + nw + q * 4 + reg;
        bool ok = node < NN;
        float ps = 0.f, pd = 0.f;
#pragma unroll
        for (int ct = 0; ct < 8; ct++) {
            float v = acc[ct][reg];
            if (ok) h2[(size_t)node * 128 + ct * 16 + r16] = __float2bfloat16(v);
            ps += v * wsv[ct];
            pd += v * wdv[ct];
        }
        for (int mask = 1; mask <= 8; mask <<= 1) {
            ps += __shfl_xor(ps, mask);
            pd += __shfl_xor(pd, mask);
        }
        if (r16 == 0 && ok) {
            as2[node] = ps;
            ad2[node] = pd;
        }
    }
}

// ---------------- Layer 2 softmax: one thread per node, UNNORMALIZED exp ----------------
__global__ void k_soft2(const int* __restrict__ srcArr, const int* __restrict__ offs,
                        const int* __restrict__ eid, const float* __restrict__ as2,
                        const float* __restrict__ ad2, float* __restrict__ alpha2) {
    int n = blockIdx.x * blockDim.x + threadIdx.x;
    if (n >= NN) return;
    int beg = offs[n], end = offs[n + 1];
    beg = min(max(beg, 0), ETOT);
    end = min(max(end, beg), ETOT);
    float adn = ad2[n];
    for (int p = beg; p < end; p++) {
        int e = eid[p];
        e = min(max(e, 0), ETOT - 1);
        int s = (e < EE) ? srcArr[e] : (e - EE);
        s = min(max(s, 0), NN - 1);
        float ev = as2[s] + adn;
        ev = ev > 0.f ? ev : 0.2f * ev;
        alpha2[p] = __expf(fminf(ev, 80.f));
    }
}

// ---------------- Layer 2 gather + fused mean-pool; divides by ssum ----------------
__global__ void k_gather2(const int* __restrict__ srcArr, const int* __restrict__ offs,
                          const int* __restrict__ eid, const bf16* __restrict__ h2,
                          const float* __restrict__ alpha2, const float* __restrict__ b2,
                          const int* __restrict__ batch, float* __restrict__ pooled) {
    int n = blockIdx.x;
    int t = threadIdx.x;        // 0..63
    int beg = offs[n], end = offs[n + 1];
    beg = min(max(beg, 0), ETOT);
    end = min(max(end, beg), ETOT);
    float a0 = 0.f, a1 = 0.f, ssum = 0.f;
    __shared__ int ls[64];
    __shared__ float la[64];
    const unsigned short* h2u = (const unsigned short*)h2;
    for (int cb = beg; cb < end; cb += 64) {
        int cnt = min(64, end - cb);
        __syncthreads();
        if (t < cnt) {
            int e = eid[cb + t];
            e = min(max(e, 0), ETOT - 1);
            int s = (e < EE) ? srcArr[e] : (e - EE);
            ls[t] = min(max(s, 0), NN - 1);
            la[t] = alpha2[cb + t];
        }
        __syncthreads();
        int j = 0;
        for (; j + 1 < cnt; j += 2) {
            int s0 = ls[j], s1 = ls[j + 1];
            float A0 = la[j], A1 = la[j + 1];
            unsigned int u0 = *(const unsigned int*)(h2u + (size_t)s0 * 128 + t * 2);
            unsigned int u1 = *(const unsigned int*)(h2u + (size_t)s1 * 128 + t * 2);
            ssum += A0 + A1;
            a0 = fmaf(A0, lo2f(u0), a0); a0 = fmaf(A1, lo2f(u1), a0);
            a1 = fmaf(A0, hi2f(u0), a1); a1 = fmaf(A1, hi2f(u1), a1);
        }
        if (j < cnt) {
            int s0 = ls[j];
            float A0 = la[j];
            unsigned int u0 = *(const unsigned int*)(h2u + (size_t)s0 * 128 + t * 2);
            ssum += A0;
            a0 = fmaf(A0, lo2f(u0), a0);
            a1 = fmaf(A0, hi2f(u0), a1);
        }
    }
    float inv = 1.f / fmaxf(ssum, 1e-35f);
    int c = t * 2;
    float r0 = a0 * inv + b2[c + 0];
    float r1 = a1 * inv + b2[c + 1];
    r0 = r0 > 0.f ? r0 : (__expf(r0) - 1.f);
    r1 = r1 > 0.f ? r1 : (__expf(r1) - 1.f);
    int b = batch[n];
    b = min(max(b, 0), BB - 1);
    atomicAdd(&pooled[b * 128 + c + 0], r0);
    atomicAdd(&pooled[b * 128 + c + 1], r1);
}

// ---------------- final linear + sigmoid (f32 output) ----------------
__global__ void k_final(const float* __restrict__ pooled, const int* __restrict__ cnt,
                        const float* __restrict__ Wl, const float* __restrict__ bl,
                        float* __restrict__ out) {
    int b = blockIdx.x * blockDim.x + threadIdx.x;
    if (b >= BB) return;
    float acc = 0.f;
    for (int k = 0; k < 128; k++) acc += pooled[b * 128 + k] * Wl[k];
    int c = cnt[b];
    float cf = (float)(c > 0 ? c : 1);
    float g = acc / cf + bl[0];
    out[b] = 1.f / (1.f + __expf(-g));
}

extern "C" void kernel_launch(void* const* d_in, const int* in_sizes, int n_in,
                              void* d_out, int out_size, void* d_ws, size_t ws_size,
                              hipStream_t stream) {
    const float* x = (const float*)d_in[0];
    const int* ei = (const int*)d_in[1];
    const int* batch = (const int*)d_in[2];
    const float* W1 = (const float*)d_in[3];
    const float* aw_s1 = (const float*)d_in[4];
    const float* aw_d1 = (const float*)d_in[5];
    const float* b1 = (const float*)d_in[6];
    const float* W2 = (const float*)d_in[7];
    const float* aw_s2 = (const float*)d_in[8];
    const float* aw_d2 = (const float*)d_in[9];
    const float* b2 = (const float*)d_in[10];
    const float* Wl = (const float*)d_in[11];
    const float* bl = (const float*)d_in[12];
    const int* srcArr = ei;
    const int* dstArr = ei + EE;

    char* w = (char*)d_ws;
    size_t off = 0;
    auto alloc = [&](size_t bytes) -> void* {
        void* p = (void*)(w + off);
        off = (off + bytes + 255) & ~(size_t)255;
        return p;
    };
    // ~71 MB proven layout
    bf16* bufA = (bf16*)alloc((size_t)NN * 256 * 2);   // h1; later h2
    bf16* bufB = (bf16*)alloc((size_t)NN * 256 * 2);   // x2
    float* alpha1 = (float*)alloc((size_t)ETOT * 4 * 4);  // reused as alpha2
    float* as1 = (float*)alloc((size_t)NN * 4 * 4);
    float* ad1 = (float*)alloc((size_t)NN * 4 * 4);
    float* as2 = (float*)alloc((size_t)NN * 4);
    float* ad2 = (float*)alloc((size_t)NN * 4);
    int* deg = (int*)alloc((size_t)NN * 4);
    int* offs = (int*)alloc((size_t)(NN + 1) * 4);
    int* cur = (int*)alloc((size_t)NN * 4);   // after k_scatter: wt1+wt2
    int* eid = (int*)alloc((size_t)ETOT * 4);
    int* bsum = (int*)alloc((size_t)NBLK * 4);
    int* boff = (int*)alloc((size_t)NBLK * 4);
    float* pooled = (float*)alloc((size_t)BB * 128 * 4);
    int* cnt = (int*)alloc((size_t)BB * 4);
    (void)ws_size;

    bf16* wt1 = (bf16*)cur;
    bf16* wt2 = (bf16*)cur + 256 * 128;

    k_init<<<256, 256, 0, stream>>>(deg, pooled, cnt);

    k_count<<<(ETOT + 255) / 256, 256, 0, stream>>>(dstArr, deg);
    k_scan1<<<NBLK, 256, 0, stream>>>(deg, offs, cur, bsum);
    k_scan2<<<1, 256, 0, stream>>>(bsum, boff, offs);
    k_scan3<<<NBLK, 256, 0, stream>>>(boff, offs, cur, batch, cnt);
    k_scatter<<<(ETOT + 255) / 256, 256, 0, stream>>>(dstArr, cur, eid);

    // cur dead -> transposed bf16 weights
    k_cvtw<<<256, 256, 0, stream>>>(W1, W2, wt1, wt2);

    bf16* h1 = bufA;
    bf16* x2 = bufB;
    k_gemm1<<<(NN + 31) / 32, 256, 0, stream>>>(x, wt1, aw_s1, aw_d1, h1, as1, ad1);
    k_soft1<<<NBLK, 256, 0, stream>>>(srcArr, offs, eid, as1, ad1, alpha1);
    k_gather1<<<NN, 64, 0, stream>>>(srcArr, offs, eid, h1, alpha1, b1, x2);

    bf16* h2 = bufA;  // h1 dead after gather1
    k_gemm2<<<(NN + 63) / 64, 256, 0, stream>>>(x2, wt2, aw_s2, aw_d2, h2, as2, ad2);

    float* alpha2 = alpha1;  // alpha1 dead after gather1
    k_soft2<<<NBLK, 256, 0, stream>>>(srcArr, offs, eid, as2, ad2, alpha2);
    k_gather2<<<NN, 64, 0, stream>>>(srcArr, offs, eid, h2, alpha2, b2, batch, pooled);

    k_final<<<2, 256, 0, stream>>>(pooled, cnt, Wl, bl, (float*)d_out);
}

// Round 14
// 440.675 us; speedup vs baseline: 2.0349x; 1.1009x over previous
//
#include <hip/hip_runtime.h>
#include <hip/hip_bf16.h>

#define NN 50000
#define EE 800000
#define ETOT 850000
#define BB 512
#define NBLK 196   // ceil(NN/256)

typedef __hip_bfloat16 bf16;
typedef __attribute__((ext_vector_type(8))) __bf16 v8bf;
typedef __attribute__((ext_vector_type(4))) float f32x4;

__device__ __forceinline__ float b2f(bf16 v) { return __bfloat162float(v); }
__device__ __forceinline__ float lo2f(unsigned int u) {
    return __uint_as_float(u << 16);
}
__device__ __forceinline__ float hi2f(unsigned int u) {
    return __uint_as_float(u & 0xffff0000u);
}
__device__ __forceinline__ unsigned short f2bfbits(float f) {
    bf16 h = __float2bfloat16(f);
    return *reinterpret_cast<unsigned short*>(&h);
}

// ---------------- fused init ----------------
__global__ void k_init(int* __restrict__ deg, float* __restrict__ pooled,
                       int* __restrict__ cnt) {
    int i = blockIdx.x * blockDim.x + threadIdx.x;
    if (i < NN) deg[i] = 0;
    if (i < BB * 128) pooled[i] = 0.f;
    if (i < BB) cnt[i] = 0;
}

// ---------------- fused weight transpose+cvt (aliases cur, after k_scatter) ----------------
__global__ void k_cvtw(const float* __restrict__ W1, const float* __restrict__ W2,
                       bf16* __restrict__ wt1, bf16* __restrict__ wt2) {
    int idx = blockIdx.x * blockDim.x + threadIdx.x;
    if (idx < 256 * 128) {
        int c = idx >> 7, k = idx & 127;
        wt1[idx] = __float2bfloat16(W1[k * 256 + c]);
    } else {
        int j = idx - 256 * 128;
        int c = j >> 8, k = j & 255;
        wt2[j] = __float2bfloat16(W2[k * 128 + c]);
    }
}

// ---------------- CSR build ----------------
__global__ void k_count(const int* __restrict__ dstArr, int* __restrict__ deg) {
    int e = blockIdx.x * blockDim.x + threadIdx.x;
    if (e >= ETOT) return;
    int d = (e < EE) ? dstArr[e] : (e - EE);
    d = min(max(d, 0), NN - 1);
    atomicAdd(&deg[d], 1);
}

__global__ void k_scan1(const int* __restrict__ deg, int* __restrict__ offs,
                        int* __restrict__ cur, int* __restrict__ bsum) {
    __shared__ int s[256];
    int t = threadIdx.x;
    int i = blockIdx.x * 256 + t;
    int v = (i < NN) ? deg[i] : 0;
    s[t] = v;
    __syncthreads();
    for (int o = 1; o < 256; o <<= 1) {
        int tv = (t >= o) ? s[t - o] : 0;
        __syncthreads();
        s[t] += tv;
        __syncthreads();
    }
    int excl = s[t] - v;
    if (i < NN) { offs[i] = excl; cur[i] = excl; }
    if (t == 255) bsum[blockIdx.x] = s[255];
}

__global__ void k_scan2(const int* __restrict__ bsum, int* __restrict__ boff,
                        int* __restrict__ offs) {
    __shared__ int s[256];
    int t = threadIdx.x;
    int v = (t < NBLK) ? bsum[t] : 0;
    s[t] = v;
    __syncthreads();
    for (int o = 1; o < 256; o <<= 1) {
        int tv = (t >= o) ? s[t - o] : 0;
        __syncthreads();
        s[t] += tv;
        __syncthreads();
    }
    if (t < NBLK) boff[t] = s[t] - v;
    if (t == 0) offs[NN] = ETOT;
}

__global__ void k_scan3(const int* __restrict__ boff, int* __restrict__ offs,
                        int* __restrict__ cur, const int* __restrict__ batch,
                        int* __restrict__ cnt) {
    int i = blockIdx.x * 256 + threadIdx.x;
    if (i < NN) {
        int b = boff[blockIdx.x];
        offs[i] += b;
        cur[i] += b;
        int g = batch[i];
        g = min(max(g, 0), BB - 1);
        atomicAdd(&cnt[g], 1);
    }
}

// scatter writes SOURCE NODE directly (no eid indirection downstream)
__global__ void k_scatter(const int* __restrict__ srcArr, const int* __restrict__ dstArr,
                          int* __restrict__ cur, int* __restrict__ csrc) {
    int e = blockIdx.x * blockDim.x + threadIdx.x;
    if (e >= ETOT) return;
    int d, s;
    if (e < EE) { d = dstArr[e]; s = srcArr[e]; }
    else        { d = e - EE;    s = d; }
    d = min(max(d, 0), NN - 1);
    s = min(max(s, 0), NN - 1);
    int p = atomicAdd(&cur[d], 1);
    if (p >= 0 && p < ETOT) csrc[p] = s;
}

// ---------------- Layer 1 GEMM via MFMA: 32 nodes/block (proven R12) ----------------
__global__ __launch_bounds__(256, 2)
void k_gemm1(const float* __restrict__ x, const bf16* __restrict__ wt1,
             const float* __restrict__ aw_s, const float* __restrict__ aw_d,
             bf16* __restrict__ h1, float* __restrict__ as1,
             float* __restrict__ ad1) {
    int n0 = blockIdx.x * 32;
    int t = threadIdx.x;
    __shared__ bf16 xs[32 * 136];
    for (int i = 0; i < 4; i++) {
        int idx = t + 256 * i;
        int r = idx >> 5, c4 = idx & 31;
        float4 v = make_float4(0.f, 0.f, 0.f, 0.f);
        if (n0 + r < NN) v = *(const float4*)(x + (size_t)(n0 + r) * 128 + c4 * 4);
        ushort4 o;
        o.x = f2bfbits(v.x); o.y = f2bfbits(v.y);
        o.z = f2bfbits(v.z); o.w = f2bfbits(v.w);
        *(ushort4*)(&xs[r * 136 + c4 * 4]) = o;
    }
    __syncthreads();

    int wv = t >> 6, lane = t & 63;
    int q = lane >> 4, r16 = lane & 15;
    int rowBase = (wv & 1) * 16;
    int colBase = (wv >> 1) * 128;

    f32x4 acc[8];
#pragma unroll
    for (int ct = 0; ct < 8; ct++) acc[ct] = (f32x4){0.f, 0.f, 0.f, 0.f};

#pragma unroll
    for (int kt = 0; kt < 4; kt++) {
        v8bf va = *(const v8bf*)(&xs[(rowBase + r16) * 136 + kt * 32 + q * 8]);
#pragma unroll
        for (int ct = 0; ct < 8; ct++) {
            v8bf vb = *(const v8bf*)(wt1 + (size_t)(colBase + ct * 16 + r16) * 128 + kt * 32 + q * 8);
            acc[ct] = __builtin_amdgcn_mfma_f32_16x16x32_bf16(va, vb, acc[ct], 0, 0, 0);
        }
    }

    float wsv[8], wdv[8];
#pragma unroll
    for (int ct = 0; ct < 8; ct++) {
        int col = colBase + ct * 16 + r16;
        wsv[ct] = aw_s[col];
        wdv[ct] = aw_d[col];
    }

    float ps[4][2], pd[4][2];
#pragma unroll
    for (int reg = 0; reg < 4; reg++) {
        ps[reg][0] = 0.f; ps[reg][1] = 0.f;
        pd[reg][0] = 0.f; pd[reg][1] = 0.f;
    }

#pragma unroll
    for (int reg = 0; reg < 4; reg++) {
        int node = n0 + rowBase + q * 4 + reg;
        bool ok = node < NN;
#pragma unroll
        for (int ct = 0; ct < 8; ct++) {
            float v = acc[ct][reg];
            if (ok) h1[(size_t)node * 256 + colBase + ct * 16 + r16] = __float2bfloat16(v);
            ps[reg][ct >> 2] += v * wsv[ct];
            pd[reg][ct >> 2] += v * wdv[ct];
        }
    }

#pragma unroll
    for (int reg = 0; reg < 4; reg++) {
        int node = n0 + rowBase + q * 4 + reg;
        bool ok = node < NN;
#pragma unroll
        for (int lh = 0; lh < 2; lh++) {
            float a = ps[reg][lh], b = pd[reg][lh];
            for (int mask = 1; mask <= 8; mask <<= 1) {
                a += __shfl_xor(a, mask);
                b += __shfl_xor(b, mask);
            }
            if (r16 == 0 && ok) {
                int head = (wv >> 1) * 2 + lh;
                as1[node * 4 + head] = a;
                ad1[node * 4 + head] = b;
            }
        }
    }
}

// ---------------- Layer 1 softmax: one thread per node, UNNORMALIZED exp ----------------
__global__ void k_soft1(const int* __restrict__ csrc, const int* __restrict__ offs,
                        const float* __restrict__ as1, const float* __restrict__ ad1,
                        float* __restrict__ alpha1) {
    int n = blockIdx.x * blockDim.x + threadIdx.x;
    if (n >= NN) return;
    int beg = offs[n], end = offs[n + 1];
    beg = min(max(beg, 0), ETOT);
    end = min(max(end, beg), ETOT);
    float4 ad = *(const float4*)&ad1[n * 4];
    for (int p = beg; p < end; p++) {
        int s = csrc[p];
        s = min(max(s, 0), NN - 1);
        float4 as = *(const float4*)&as1[s * 4];
        float4 w;
        float ev;
        ev = as.x + ad.x; ev = ev > 0.f ? ev : 0.2f * ev; w.x = __expf(fminf(ev, 80.f));
        ev = as.y + ad.y; ev = ev > 0.f ? ev : 0.2f * ev; w.y = __expf(fminf(ev, 80.f));
        ev = as.z + ad.z; ev = ev > 0.f ? ev : 0.2f * ev; w.z = __expf(fminf(ev, 80.f));
        ev = as.w + ad.w; ev = ev > 0.f ? ev : 0.2f * ev; w.w = __expf(fminf(ev, 80.f));
        *(float4*)&alpha1[(size_t)p * 4] = w;
    }
}

// ---------------- Layer 1 gather: one wave per node; 4-deep unroll ----------------
__global__ void k_gather1(const int* __restrict__ csrc, const int* __restrict__ offs,
                          const bf16* __restrict__ h1, const float* __restrict__ alpha1,
                          const float* __restrict__ b1, bf16* __restrict__ x2) {
    int n = blockIdx.x;
    int t = threadIdx.x;        // 0..63
    int h = t >> 4;
    int beg = offs[n], end = offs[n + 1];
    beg = min(max(beg, 0), ETOT);
    end = min(max(end, beg), ETOT);
    float a0 = 0.f, a1 = 0.f, a2 = 0.f, a3 = 0.f, ssum = 0.f;
    __shared__ int ls[64];
    __shared__ float la[64 * 4];
    const unsigned short* h1u = (const unsigned short*)h1;
    for (int cb = beg; cb < end; cb += 64) {
        int cnt = min(64, end - cb);
        __syncthreads();
        if (t < cnt) {
            int s = csrc[cb + t];
            ls[t] = min(max(s, 0), NN - 1);
            *(float4*)&la[t * 4] = *(const float4*)&alpha1[(size_t)(cb + t) * 4];
        }
        __syncthreads();
        int j = 0;
        for (; j + 3 < cnt; j += 4) {
            int s0 = ls[j], s1 = ls[j + 1], s2 = ls[j + 2], s3 = ls[j + 3];
            float A0 = la[j * 4 + h], A1 = la[j * 4 + 4 + h];
            float A2 = la[j * 4 + 8 + h], A3 = la[j * 4 + 12 + h];
            uint2 u0 = *(const uint2*)(h1u + (size_t)s0 * 256 + t * 4);
            uint2 u1 = *(const uint2*)(h1u + (size_t)s1 * 256 + t * 4);
            uint2 u2 = *(const uint2*)(h1u + (size_t)s2 * 256 + t * 4);
            uint2 u3 = *(const uint2*)(h1u + (size_t)s3 * 256 + t * 4);
            ssum += (A0 + A1) + (A2 + A3);
            a0 = fmaf(A0, lo2f(u0.x), a0); a0 = fmaf(A1, lo2f(u1.x), a0);
            a0 = fmaf(A2, lo2f(u2.x), a0); a0 = fmaf(A3, lo2f(u3.x), a0);
            a1 = fmaf(A0, hi2f(u0.x), a1); a1 = fmaf(A1, hi2f(u1.x), a1);
            a1 = fmaf(A2, hi2f(u2.x), a1); a1 = fmaf(A3, hi2f(u3.x), a1);
            a2 = fmaf(A0, lo2f(u0.y), a2); a2 = fmaf(A1, lo2f(u1.y), a2);
            a2 = fmaf(A2, lo2f(u2.y), a2); a2 = fmaf(A3, lo2f(u3.y), a2);
            a3 = fmaf(A0, hi2f(u0.y), a3); a3 = fmaf(A1, hi2f(u1.y), a3);
            a3 = fmaf(A2, hi2f(u2.y), a3); a3 = fmaf(A3, hi2f(u3.y), a3);
        }
        for (; j < cnt; j++) {
            int s0 = ls[j];
            float A0 = la[j * 4 + h];
            uint2 u0 = *(const uint2*)(h1u + (size_t)s0 * 256 + t * 4);
            ssum += A0;
            a0 = fmaf(A0, lo2f(u0.x), a0);
            a1 = fmaf(A0, hi2f(u0.x), a1);
            a2 = fmaf(A0, lo2f(u0.y), a2);
            a3 = fmaf(A0, hi2f(u0.y), a3);
        }
    }
    float inv = 1.f / fmaxf(ssum, 1e-35f);
    int c = t * 4;
    float r0 = a0 * inv + b1[c + 0];
    float r1 = a1 * inv + b1[c + 1];
    float r2 = a2 * inv + b1[c + 2];
    float r3 = a3 * inv + b1[c + 3];
    r0 = r0 > 0.f ? r0 : (__expf(r0) - 1.f);
    r1 = r1 > 0.f ? r1 : (__expf(r1) - 1.f);
    r2 = r2 > 0.f ? r2 : (__expf(r2) - 1.f);
    r3 = r3 > 0.f ? r3 : (__expf(r3) - 1.f);
    bf16* xr = x2 + (size_t)n * 256 + c;
    xr[0] = __float2bfloat16(r0);
    xr[1] = __float2bfloat16(r1);
    xr[2] = __float2bfloat16(r2);
    xr[3] = __float2bfloat16(r3);
}

// ---------------- Layer 2 GEMM via MFMA ----------------
__global__ void k_gemm2(const bf16* __restrict__ x2, const bf16* __restrict__ wt2,
                        const float* __restrict__ aw_s, const float* __restrict__ aw_d,
                        bf16* __restrict__ h2, float* __restrict__ as2,
                        float* __restrict__ ad2) {
    int n0 = blockIdx.x * 64;
    int t = threadIdx.x;
    __shared__ bf16 xs[64 * 264];
    for (int i = 0; i < 8; i++) {
        int idx = t + 256 * i;
        int r = idx >> 5, c8 = idx & 31;
        uint4 v;
        if (n0 + r < NN) v = *(const uint4*)(x2 + (size_t)(n0 + r) * 256 + c8 * 8);
        else             v = make_uint4(0, 0, 0, 0);
        *(uint4*)(&xs[r * 264 + c8 * 8]) = v;
    }
    __syncthreads();

    int wv = t >> 6, lane = t & 63;
    int q = lane >> 4, r16 = lane & 15;
    int nw = wv * 16;

    f32x4 acc[8];
#pragma unroll
    for (int ct = 0; ct < 8; ct++) acc[ct] = (f32x4){0.f, 0.f, 0.f, 0.f};

#pragma unroll
    for (int kt = 0; kt < 8; kt++) {
        v8bf va = *(const v8bf*)(&xs[(nw + r16) * 264 + kt * 32 + q * 8]);
#pragma unroll
        for (int ct = 0; ct < 8; ct++) {
            v8bf vb = *(const v8bf*)(wt2 + (size_t)(ct * 16 + r16) * 256 + kt * 32 + q * 8);
            acc[ct] = __builtin_amdgcn_mfma_f32_16x16x32_bf16(va, vb, acc[ct], 0, 0, 0);
        }
    }

    float wsv[8], wdv[8];
#pragma unroll
    for (int ct = 0; ct < 8; ct++) {
        int col = ct * 16 + r16;
        wsv[ct] = aw_s[col];
        wdv[ct] = aw_d[col];
    }

#pragma unroll
    for (int reg = 0; reg < 4; reg++) {
        int node = n0 + nw + q * 4 + reg;
        bool ok = node < NN;
        float ps = 0.f, pd = 0.f;
#pragma unroll
        for (int ct = 0; ct < 8; ct++) {
            float v = acc[ct][reg];
            if (ok) h2[(size_t)node * 128 + ct * 16 + r16] = __float2bfloat16(v);
            ps += v * wsv[ct];
            pd += v * wdv[ct];
        }
        for (int mask = 1; mask <= 8; mask <<= 1) {
            ps += __shfl_xor(ps, mask);
            pd += __shfl_xor(pd, mask);
        }
        if (r16 == 0 && ok) {
            as2[node] = ps;
            ad2[node] = pd;
        }
    }
}

// ---------------- Layer 2 softmax: one thread per node, UNNORMALIZED exp ----------------
__global__ void k_soft2(const int* __restrict__ csrc, const int* __restrict__ offs,
                        const float* __restrict__ as2, const float* __restrict__ ad2,
                        float* __restrict__ alpha2) {
    int n = blockIdx.x * blockDim.x + threadIdx.x;
    if (n >= NN) return;
    int beg = offs[n], end = offs[n + 1];
    beg = min(max(beg, 0), ETOT);
    end = min(max(end, beg), ETOT);
    float adn = ad2[n];
    for (int p = beg; p < end; p++) {
        int s = csrc[p];
        s = min(max(s, 0), NN - 1);
        float ev = as2[s] + adn;
        ev = ev > 0.f ? ev : 0.2f * ev;
        alpha2[p] = __expf(fminf(ev, 80.f));
    }
}

// ---------------- Layer 2 gather + fused mean-pool; 4-deep unroll ----------------
__global__ void k_gather2(const int* __restrict__ csrc, const int* __restrict__ offs,
                          const bf16* __restrict__ h2, const float* __restrict__ alpha2,
                          const float* __restrict__ b2, const int* __restrict__ batch,
                          float* __restrict__ pooled) {
    int n = blockIdx.x;
    int t = threadIdx.x;        // 0..63
    int beg = offs[n], end = offs[n + 1];
    beg = min(max(beg, 0), ETOT);
    end = min(max(end, beg), ETOT);
    float a0 = 0.f, a1 = 0.f, ssum = 0.f;
    __shared__ int ls[64];
    __shared__ float la[64];
    const unsigned short* h2u = (const unsigned short*)h2;
    for (int cb = beg; cb < end; cb += 64) {
        int cnt = min(64, end - cb);
        __syncthreads();
        if (t < cnt) {
            int s = csrc[cb + t];
            ls[t] = min(max(s, 0), NN - 1);
            la[t] = alpha2[cb + t];
        }
        __syncthreads();
        int j = 0;
        for (; j + 3 < cnt; j += 4) {
            int s0 = ls[j], s1 = ls[j + 1], s2 = ls[j + 2], s3 = ls[j + 3];
            float A0 = la[j], A1 = la[j + 1], A2 = la[j + 2], A3 = la[j + 3];
            unsigned int u0 = *(const unsigned int*)(h2u + (size_t)s0 * 128 + t * 2);
            unsigned int u1 = *(const unsigned int*)(h2u + (size_t)s1 * 128 + t * 2);
            unsigned int u2 = *(const unsigned int*)(h2u + (size_t)s2 * 128 + t * 2);
            unsigned int u3 = *(const unsigned int*)(h2u + (size_t)s3 * 128 + t * 2);
            ssum += (A0 + A1) + (A2 + A3);
            a0 = fmaf(A0, lo2f(u0), a0); a0 = fmaf(A1, lo2f(u1), a0);
            a0 = fmaf(A2, lo2f(u2), a0); a0 = fmaf(A3, lo2f(u3), a0);
            a1 = fmaf(A0, hi2f(u0), a1); a1 = fmaf(A1, hi2f(u1), a1);
            a1 = fmaf(A2, hi2f(u2), a1); a1 = fmaf(A3, hi2f(u3), a1);
        }
        for (; j < cnt; j++) {
            int s0 = ls[j];
            float A0 = la[j];
            unsigned int u0 = *(const unsigned int*)(h2u + (size_t)s0 * 128 + t * 2);
            ssum += A0;
            a0 = fmaf(A0, lo2f(u0), a0);
            a1 = fmaf(A0, hi2f(u0), a1);
        }
    }
    float inv = 1.f / fmaxf(ssum, 1e-35f);
    int c = t * 2;
    float r0 = a0 * inv + b2[c + 0];
    float r1 = a1 * inv + b2[c + 1];
    r0 = r0 > 0.f ? r0 : (__expf(r0) - 1.f);
    r1 = r1 > 0.f ? r1 : (__expf(r1) - 1.f);
    int b = batch[n];
    b = min(max(b, 0), BB - 1);
    atomicAdd(&pooled[b * 128 + c + 0], r0);
    atomicAdd(&pooled[b * 128 + c + 1], r1);
}

// ---------------- final linear + sigmoid (f32 output) ----------------
__global__ void k_final(const float* __restrict__ pooled, const int* __restrict__ cnt,
                        const float* __restrict__ Wl, const float* __restrict__ bl,
                        float* __restrict__ out) {
    int b = blockIdx.x * blockDim.x + threadIdx.x;
    if (b >= BB) return;
    float acc = 0.f;
    for (int k = 0; k < 128; k++) acc += pooled[b * 128 + k] * Wl[k];
    int c = cnt[b];
    float cf = (float)(c > 0 ? c : 1);
    float g = acc / cf + bl[0];
    out[b] = 1.f / (1.f + __expf(-g));
}

extern "C" void kernel_launch(void* const* d_in, const int* in_sizes, int n_in,
                              void* d_out, int out_size, void* d_ws, size_t ws_size,
                              hipStream_t stream) {
    const float* x = (const float*)d_in[0];
    const int* ei = (const int*)d_in[1];
    const int* batch = (const int*)d_in[2];
    const float* W1 = (const float*)d_in[3];
    const float* aw_s1 = (const float*)d_in[4];
    const float* aw_d1 = (const float*)d_in[5];
    const float* b1 = (const float*)d_in[6];
    const float* W2 = (const float*)d_in[7];
    const float* aw_s2 = (const float*)d_in[8];
    const float* aw_d2 = (const float*)d_in[9];
    const float* b2 = (const float*)d_in[10];
    const float* Wl = (const float*)d_in[11];
    const float* bl = (const float*)d_in[12];
    const int* srcArr = ei;
    const int* dstArr = ei + EE;

    char* w = (char*)d_ws;
    size_t off = 0;
    auto alloc = [&](size_t bytes) -> void* {
        void* p = (void*)(w + off);
        off = (off + bytes + 255) & ~(size_t)255;
        return p;
    };
    // ~71 MB proven layout (csrc replaces eid, same size)
    bf16* bufA = (bf16*)alloc((size_t)NN * 256 * 2);   // h1; later h2
    bf16* bufB = (bf16*)alloc((size_t)NN * 256 * 2);   // x2
    float* alpha1 = (float*)alloc((size_t)ETOT * 4 * 4);  // reused as alpha2
    float* as1 = (float*)alloc((size_t)NN * 4 * 4);
    float* ad1 = (float*)alloc((size_t)NN * 4 * 4);
    float* as2 = (float*)alloc((size_t)NN * 4);
    float* ad2 = (float*)alloc((size_t)NN * 4);
    int* deg = (int*)alloc((size_t)NN * 4);
    int* offs = (int*)alloc((size_t)(NN + 1) * 4);
    int* cur = (int*)alloc((size_t)NN * 4);   // after k_scatter: wt1+wt2
    int* csrc = (int*)alloc((size_t)ETOT * 4);
    int* bsum = (int*)alloc((size_t)NBLK * 4);
    int* boff = (int*)alloc((size_t)NBLK * 4);
    float* pooled = (float*)alloc((size_t)BB * 128 * 4);
    int* cnt = (int*)alloc((size_t)BB * 4);
    (void)ws_size;

    bf16* wt1 = (bf16*)cur;
    bf16* wt2 = (bf16*)cur + 256 * 128;

    k_init<<<256, 256, 0, stream>>>(deg, pooled, cnt);

    k_count<<<(ETOT + 255) / 256, 256, 0, stream>>>(dstArr, deg);
    k_scan1<<<NBLK, 256, 0, stream>>>(deg, offs, cur, bsum);
    k_scan2<<<1, 256, 0, stream>>>(bsum, boff, offs);
    k_scan3<<<NBLK, 256, 0, stream>>>(boff, offs, cur, batch, cnt);
    k_scatter<<<(ETOT + 255) / 256, 256, 0, stream>>>(srcArr, dstArr, cur, csrc);

    // cur dead -> transposed bf16 weights
    k_cvtw<<<256, 256, 0, stream>>>(W1, W2, wt1, wt2);

    bf16* h1 = bufA;
    bf16* x2 = bufB;
    k_gemm1<<<(NN + 31) / 32, 256, 0, stream>>>(x, wt1, aw_s1, aw_d1, h1, as1, ad1);
    k_soft1<<<NBLK, 256, 0, stream>>>(csrc, offs, as1, ad1, alpha1);
    k_gather1<<<NN, 64, 0, stream>>>(csrc, offs, h1, alpha1, b1, x2);

    bf16* h2 = bufA;  // h1 dead after gather1
    k_gemm2<<<(NN + 63) / 64, 256, 0, stream>>>(x2, wt2, aw_s2, aw_d2, h2, as2, ad2);

    float* alpha2 = alpha1;  // alpha1 dead after gather1
    k_soft2<<<NBLK, 256, 0, stream>>>(csrc, offs, as2, ad2, alpha2);
    k_gather2<<<NN, 64, 0, stream>>>(csrc, offs, h2, alpha2, b2, batch, pooled);

    k_final<<<2, 256, 0, stream>>>(pooled, cnt, Wl, bl, (float*)d_out);
}

// Round 15
// 412.300 us; speedup vs baseline: 2.1749x; 1.0688x over previous
//
#include <hip/hip_runtime.h>
#include <hip/hip_bf16.h>

#define NN 50000
#define EE 800000
#define ETOT 850000
#define BB 512
#define NBLK 196   // ceil(NN/256)

typedef __hip_bfloat16 bf16;
typedef __attribute__((ext_vector_type(8))) __bf16 v8bf;
typedef __attribute__((ext_vector_type(4))) float f32x4;

__device__ __forceinline__ float b2f(bf16 v) { return __bfloat162float(v); }
__device__ __forceinline__ float lo2f(unsigned int u) {
    return __uint_as_float(u << 16);
}
__device__ __forceinline__ float hi2f(unsigned int u) {
    return __uint_as_float(u & 0xffff0000u);
}
__device__ __forceinline__ unsigned short f2bfbits(float f) {
    bf16 h = __float2bfloat16(f);
    return *reinterpret_cast<unsigned short*>(&h);
}
__device__ __forceinline__ float lrelu_exp(float ev) {
    ev = ev > 0.f ? ev : 0.2f * ev;
    return __expf(fminf(ev, 80.f));
}

// ---------------- fused init ----------------
__global__ void k_init(int* __restrict__ deg, float* __restrict__ pooled,
                       int* __restrict__ cnt) {
    int i = blockIdx.x * blockDim.x + threadIdx.x;
    if (i < NN) deg[i] = 0;
    if (i < BB * 128) pooled[i] = 0.f;
    if (i < BB) cnt[i] = 0;
}

// ---------------- fused weight transpose+cvt (aliases cur, after k_scatter) ----------------
__global__ void k_cvtw(const float* __restrict__ W1, const float* __restrict__ W2,
                       bf16* __restrict__ wt1, bf16* __restrict__ wt2) {
    int idx = blockIdx.x * blockDim.x + threadIdx.x;
    if (idx < 256 * 128) {
        int c = idx >> 7, k = idx & 127;
        wt1[idx] = __float2bfloat16(W1[k * 256 + c]);
    } else {
        int j = idx - 256 * 128;
        int c = j >> 8, k = j & 255;
        wt2[j] = __float2bfloat16(W2[k * 128 + c]);
    }
}

// ---------------- CSR build ----------------
__global__ void k_count(const int* __restrict__ dstArr, int* __restrict__ deg) {
    int e = blockIdx.x * blockDim.x + threadIdx.x;
    if (e >= ETOT) return;
    int d = (e < EE) ? dstArr[e] : (e - EE);
    d = min(max(d, 0), NN - 1);
    atomicAdd(&deg[d], 1);
}

__global__ void k_scan1(const int* __restrict__ deg, int* __restrict__ offs,
                        int* __restrict__ cur, int* __restrict__ bsum) {
    __shared__ int s[256];
    int t = threadIdx.x;
    int i = blockIdx.x * 256 + t;
    int v = (i < NN) ? deg[i] : 0;
    s[t] = v;
    __syncthreads();
    for (int o = 1; o < 256; o <<= 1) {
        int tv = (t >= o) ? s[t - o] : 0;
        __syncthreads();
        s[t] += tv;
        __syncthreads();
    }
    int excl = s[t] - v;
    if (i < NN) { offs[i] = excl; cur[i] = excl; }
    if (t == 255) bsum[blockIdx.x] = s[255];
}

__global__ void k_scan2(const int* __restrict__ bsum, int* __restrict__ boff,
                        int* __restrict__ offs) {
    __shared__ int s[256];
    int t = threadIdx.x;
    int v = (t < NBLK) ? bsum[t] : 0;
    s[t] = v;
    __syncthreads();
    for (int o = 1; o < 256; o <<= 1) {
        int tv = (t >= o) ? s[t - o] : 0;
        __syncthreads();
        s[t] += tv;
        __syncthreads();
    }
    if (t < NBLK) boff[t] = s[t] - v;
    if (t == 0) offs[NN] = ETOT;
}

__global__ void k_scan3(const int* __restrict__ boff, int* __restrict__ offs,
                        int* __restrict__ cur, const int* __restrict__ batch,
                        int* __restrict__ cnt) {
    int i = blockIdx.x * 256 + threadIdx.x;
    if (i < NN) {
        int b = boff[blockIdx.x];
        offs[i] += b;
        cur[i] += b;
        int g = batch[i];
        g = min(max(g, 0), BB - 1);
        atomicAdd(&cnt[g], 1);
    }
}

__global__ void k_scatter(const int* __restrict__ srcArr, const int* __restrict__ dstArr,
                          int* __restrict__ cur, int* __restrict__ csrc) {
    int e = blockIdx.x * blockDim.x + threadIdx.x;
    if (e >= ETOT) return;
    int d, s;
    if (e < EE) { d = dstArr[e]; s = srcArr[e]; }
    else        { d = e - EE;    s = d; }
    d = min(max(d, 0), NN - 1);
    s = min(max(s, 0), NN - 1);
    int p = atomicAdd(&cur[d], 1);
    if (p >= 0 && p < ETOT) csrc[p] = s;
}

// ---------------- Layer 1 GEMM via MFMA: 32 nodes/block (proven R12) ----------------
__global__ __launch_bounds__(256, 2)
void k_gemm1(const float* __restrict__ x, const bf16* __restrict__ wt1,
             const float* __restrict__ aw_s, const float* __restrict__ aw_d,
             bf16* __restrict__ h1, float* __restrict__ as1,
             float* __restrict__ ad1) {
    int n0 = blockIdx.x * 32;
    int t = threadIdx.x;
    __shared__ bf16 xs[32 * 136];
    for (int i = 0; i < 4; i++) {
        int idx = t + 256 * i;
        int r = idx >> 5, c4 = idx & 31;
        float4 v = make_float4(0.f, 0.f, 0.f, 0.f);
        if (n0 + r < NN) v = *(const float4*)(x + (size_t)(n0 + r) * 128 + c4 * 4);
        ushort4 o;
        o.x = f2bfbits(v.x); o.y = f2bfbits(v.y);
        o.z = f2bfbits(v.z); o.w = f2bfbits(v.w);
        *(ushort4*)(&xs[r * 136 + c4 * 4]) = o;
    }
    __syncthreads();

    int wv = t >> 6, lane = t & 63;
    int q = lane >> 4, r16 = lane & 15;
    int rowBase = (wv & 1) * 16;
    int colBase = (wv >> 1) * 128;

    f32x4 acc[8];
#pragma unroll
    for (int ct = 0; ct < 8; ct++) acc[ct] = (f32x4){0.f, 0.f, 0.f, 0.f};

#pragma unroll
    for (int kt = 0; kt < 4; kt++) {
        v8bf va = *(const v8bf*)(&xs[(rowBase + r16) * 136 + kt * 32 + q * 8]);
#pragma unroll
        for (int ct = 0; ct < 8; ct++) {
            v8bf vb = *(const v8bf*)(wt1 + (size_t)(colBase + ct * 16 + r16) * 128 + kt * 32 + q * 8);
            acc[ct] = __builtin_amdgcn_mfma_f32_16x16x32_bf16(va, vb, acc[ct], 0, 0, 0);
        }
    }

    float wsv[8], wdv[8];
#pragma unroll
    for (int ct = 0; ct < 8; ct++) {
        int col = colBase + ct * 16 + r16;
        wsv[ct] = aw_s[col];
        wdv[ct] = aw_d[col];
    }

    float ps[4][2], pd[4][2];
#pragma unroll
    for (int reg = 0; reg < 4; reg++) {
        ps[reg][0] = 0.f; ps[reg][1] = 0.f;
        pd[reg][0] = 0.f; pd[reg][1] = 0.f;
    }

#pragma unroll
    for (int reg = 0; reg < 4; reg++) {
        int node = n0 + rowBase + q * 4 + reg;
        bool ok = node < NN;
#pragma unroll
        for (int ct = 0; ct < 8; ct++) {
            float v = acc[ct][reg];
            if (ok) h1[(size_t)node * 256 + colBase + ct * 16 + r16] = __float2bfloat16(v);
            ps[reg][ct >> 2] += v * wsv[ct];
            pd[reg][ct >> 2] += v * wdv[ct];
        }
    }

#pragma unroll
    for (int reg = 0; reg < 4; reg++) {
        int node = n0 + rowBase + q * 4 + reg;
        bool ok = node < NN;
#pragma unroll
        for (int lh = 0; lh < 2; lh++) {
            float a = ps[reg][lh], b = pd[reg][lh];
            for (int mask = 1; mask <= 8; mask <<= 1) {
                a += __shfl_xor(a, mask);
                b += __shfl_xor(b, mask);
            }
            if (r16 == 0 && ok) {
                int head = (wv >> 1) * 2 + lh;
                as1[node * 4 + head] = a;
                ad1[node * 4 + head] = b;
            }
        }
    }
}

// ---------------- Layer 1 gather with FUSED softmax weights ----------------
__global__ void k_gather1(const int* __restrict__ csrc, const int* __restrict__ offs,
                          const bf16* __restrict__ h1, const float* __restrict__ as1,
                          const float* __restrict__ ad1, const float* __restrict__ b1,
                          bf16* __restrict__ x2) {
    int n = blockIdx.x;
    int t = threadIdx.x;        // 0..63
    int h = t >> 4;
    int beg = offs[n], end = offs[n + 1];
    beg = min(max(beg, 0), ETOT);
    end = min(max(end, beg), ETOT);
    float4 ad = *(const float4*)&ad1[n * 4];   // wave-uniform
    float a0 = 0.f, a1 = 0.f, a2 = 0.f, a3 = 0.f, ssum = 0.f;
    __shared__ int ls[64];
    __shared__ float la[64 * 4];
    const unsigned short* h1u = (const unsigned short*)h1;
    for (int cb = beg; cb < end; cb += 64) {
        int cnt = min(64, end - cb);
        __syncthreads();
        if (t < cnt) {
            int s = csrc[cb + t];
            s = min(max(s, 0), NN - 1);
            ls[t] = s;
            float4 as = *(const float4*)&as1[s * 4];   // 800 KB table, L2-hit
            float4 w;
            w.x = lrelu_exp(as.x + ad.x);
            w.y = lrelu_exp(as.y + ad.y);
            w.z = lrelu_exp(as.z + ad.z);
            w.w = lrelu_exp(as.w + ad.w);
            *(float4*)&la[t * 4] = w;
        }
        __syncthreads();
        int j = 0;
        for (; j + 3 < cnt; j += 4) {
            int s0 = ls[j], s1 = ls[j + 1], s2 = ls[j + 2], s3 = ls[j + 3];
            float A0 = la[j * 4 + h], A1 = la[j * 4 + 4 + h];
            float A2 = la[j * 4 + 8 + h], A3 = la[j * 4 + 12 + h];
            uint2 u0 = *(const uint2*)(h1u + (size_t)s0 * 256 + t * 4);
            uint2 u1 = *(const uint2*)(h1u + (size_t)s1 * 256 + t * 4);
            uint2 u2 = *(const uint2*)(h1u + (size_t)s2 * 256 + t * 4);
            uint2 u3 = *(const uint2*)(h1u + (size_t)s3 * 256 + t * 4);
            ssum += (A0 + A1) + (A2 + A3);
            a0 = fmaf(A0, lo2f(u0.x), a0); a0 = fmaf(A1, lo2f(u1.x), a0);
            a0 = fmaf(A2, lo2f(u2.x), a0); a0 = fmaf(A3, lo2f(u3.x), a0);
            a1 = fmaf(A0, hi2f(u0.x), a1); a1 = fmaf(A1, hi2f(u1.x), a1);
            a1 = fmaf(A2, hi2f(u2.x), a1); a1 = fmaf(A3, hi2f(u3.x), a1);
            a2 = fmaf(A0, lo2f(u0.y), a2); a2 = fmaf(A1, lo2f(u1.y), a2);
            a2 = fmaf(A2, lo2f(u2.y), a2); a2 = fmaf(A3, lo2f(u3.y), a2);
            a3 = fmaf(A0, hi2f(u0.y), a3); a3 = fmaf(A1, hi2f(u1.y), a3);
            a3 = fmaf(A2, hi2f(u2.y), a3); a3 = fmaf(A3, hi2f(u3.y), a3);
        }
        for (; j < cnt; j++) {
            int s0 = ls[j];
            float A0 = la[j * 4 + h];
            uint2 u0 = *(const uint2*)(h1u + (size_t)s0 * 256 + t * 4);
            ssum += A0;
            a0 = fmaf(A0, lo2f(u0.x), a0);
            a1 = fmaf(A0, hi2f(u0.x), a1);
            a2 = fmaf(A0, lo2f(u0.y), a2);
            a3 = fmaf(A0, hi2f(u0.y), a3);
        }
    }
    float inv = 1.f / fmaxf(ssum, 1e-35f);
    int c = t * 4;
    float r0 = a0 * inv + b1[c + 0];
    float r1 = a1 * inv + b1[c + 1];
    float r2 = a2 * inv + b1[c + 2];
    float r3 = a3 * inv + b1[c + 3];
    r0 = r0 > 0.f ? r0 : (__expf(r0) - 1.f);
    r1 = r1 > 0.f ? r1 : (__expf(r1) - 1.f);
    r2 = r2 > 0.f ? r2 : (__expf(r2) - 1.f);
    r3 = r3 > 0.f ? r3 : (__expf(r3) - 1.f);
    bf16* xr = x2 + (size_t)n * 256 + c;
    xr[0] = __float2bfloat16(r0);
    xr[1] = __float2bfloat16(r1);
    xr[2] = __float2bfloat16(r2);
    xr[3] = __float2bfloat16(r3);
}

// ---------------- Layer 2 GEMM via MFMA ----------------
__global__ void k_gemm2(const bf16* __restrict__ x2, const bf16* __restrict__ wt2,
                        const float* __restrict__ aw_s, const float* __restrict__ aw_d,
                        bf16* __restrict__ h2, float* __restrict__ as2,
                        float* __restrict__ ad2) {
    int n0 = blockIdx.x * 64;
    int t = threadIdx.x;
    __shared__ bf16 xs[64 * 264];
    for (int i = 0; i < 8; i++) {
        int idx = t + 256 * i;
        int r = idx >> 5, c8 = idx & 31;
        uint4 v;
        if (n0 + r < NN) v = *(const uint4*)(x2 + (size_t)(n0 + r) * 256 + c8 * 8);
        else             v = make_uint4(0, 0, 0, 0);
        *(uint4*)(&xs[r * 264 + c8 * 8]) = v;
    }
    __syncthreads();

    int wv = t >> 6, lane = t & 63;
    int q = lane >> 4, r16 = lane & 15;
    int nw = wv * 16;

    f32x4 acc[8];
#pragma unroll
    for (int ct = 0; ct < 8; ct++) acc[ct] = (f32x4){0.f, 0.f, 0.f, 0.f};

#pragma unroll
    for (int kt = 0; kt < 8; kt++) {
        v8bf va = *(const v8bf*)(&xs[(nw + r16) * 264 + kt * 32 + q * 8]);
#pragma unroll
        for (int ct = 0; ct < 8; ct++) {
            v8bf vb = *(const v8bf*)(wt2 + (size_t)(ct * 16 + r16) * 256 + kt * 32 + q * 8);
            acc[ct] = __builtin_amdgcn_mfma_f32_16x16x32_bf16(va, vb, acc[ct], 0, 0, 0);
        }
    }

    float wsv[8], wdv[8];
#pragma unroll
    for (int ct = 0; ct < 8; ct++) {
        int col = ct * 16 + r16;
        wsv[ct] = aw_s[col];
        wdv[ct] = aw_d[col];
    }

#pragma unroll
    for (int reg = 0; reg < 4; reg++) {
        int node = n0 + nw + q * 4 + reg;
        bool ok = node < NN;
        float ps = 0.f, pd = 0.f;
#pragma unroll
        for (int ct = 0; ct < 8; ct++) {
            float v = acc[ct][reg];
            if (ok) h2[(size_t)node * 128 + ct * 16 + r16] = __float2bfloat16(v);
            ps += v * wsv[ct];
            pd += v * wdv[ct];
        }
        for (int mask = 1; mask <= 8; mask <<= 1) {
            ps += __shfl_xor(ps, mask);
            pd += __shfl_xor(pd, mask);
        }
        if (r16 == 0 && ok) {
            as2[node] = ps;
            ad2[node] = pd;
        }
    }
}

// ---------------- Layer 2 gather with FUSED softmax + mean-pool ----------------
__global__ void k_gather2(const int* __restrict__ csrc, const int* __restrict__ offs,
                          const bf16* __restrict__ h2, const float* __restrict__ as2,
                          const float* __restrict__ ad2, const float* __restrict__ b2,
                          const int* __restrict__ batch, float* __restrict__ pooled) {
    int n = blockIdx.x;
    int t = threadIdx.x;        // 0..63
    int beg = offs[n], end = offs[n + 1];
    beg = min(max(beg, 0), ETOT);
    end = min(max(end, beg), ETOT);
    float adn = ad2[n];
    float a0 = 0.f, a1 = 0.f, ssum = 0.f;
    __shared__ int ls[64];
    __shared__ float la[64];
    const unsigned short* h2u = (const unsigned short*)h2;
    for (int cb = beg; cb < end; cb += 64) {
        int cnt = min(64, end - cb);
        __syncthreads();
        if (t < cnt) {
            int s = csrc[cb + t];
            s = min(max(s, 0), NN - 1);
            ls[t] = s;
            la[t] = lrelu_exp(as2[s] + adn);   // 200 KB table, L2-hit
        }
        __syncthreads();
        int j = 0;
        for (; j + 3 < cnt; j += 4) {
            int s0 = ls[j], s1 = ls[j + 1], s2 = ls[j + 2], s3 = ls[j + 3];
            float A0 = la[j], A1 = la[j + 1], A2 = la[j + 2], A3 = la[j + 3];
            unsigned int u0 = *(const unsigned int*)(h2u + (size_t)s0 * 128 + t * 2);
            unsigned int u1 = *(const unsigned int*)(h2u + (size_t)s1 * 128 + t * 2);
            unsigned int u2 = *(const unsigned int*)(h2u + (size_t)s2 * 128 + t * 2);
            unsigned int u3 = *(const unsigned int*)(h2u + (size_t)s3 * 128 + t * 2);
            ssum += (A0 + A1) + (A2 + A3);
            a0 = fmaf(A0, lo2f(u0), a0); a0 = fmaf(A1, lo2f(u1), a0);
            a0 = fmaf(A2, lo2f(u2), a0); a0 = fmaf(A3, lo2f(u3), a0);
            a1 = fmaf(A0, hi2f(u0), a1); a1 = fmaf(A1, hi2f(u1), a1);
            a1 = fmaf(A2, hi2f(u2), a1); a1 = fmaf(A3, hi2f(u3), a1);
        }
        for (; j < cnt; j++) {
            int s0 = ls[j];
            float A0 = la[j];
            unsigned int u0 = *(const unsigned int*)(h2u + (size_t)s0 * 128 + t * 2);
            ssum += A0;
            a0 = fmaf(A0, lo2f(u0), a0);
            a1 = fmaf(A0, hi2f(u0), a1);
        }
    }
    float inv = 1.f / fmaxf(ssum, 1e-35f);
    int c = t * 2;
    float r0 = a0 * inv + b2[c + 0];
    float r1 = a1 * inv + b2[c + 1];
    r0 = r0 > 0.f ? r0 : (__expf(r0) - 1.f);
    r1 = r1 > 0.f ? r1 : (__expf(r1) - 1.f);
    int b = batch[n];
    b = min(max(b, 0), BB - 1);
    atomicAdd(&pooled[b * 128 + c + 0], r0);
    atomicAdd(&pooled[b * 128 + c + 1], r1);
}

// ---------------- final linear + sigmoid (f32 output) ----------------
__global__ void k_final(const float* __restrict__ pooled, const int* __restrict__ cnt,
                        const float* __restrict__ Wl, const float* __restrict__ bl,
                        float* __restrict__ out) {
    int b = blockIdx.x * blockDim.x + threadIdx.x;
    if (b >= BB) return;
    float acc = 0.f;
    for (int k = 0; k < 128; k++) acc += pooled[b * 128 + k] * Wl[k];
    int c = cnt[b];
    float cf = (float)(c > 0 ? c : 1);
    float g = acc / cf + bl[0];
    out[b] = 1.f / (1.f + __expf(-g));
}

extern "C" void kernel_launch(void* const* d_in, const int* in_sizes, int n_in,
                              void* d_out, int out_size, void* d_ws, size_t ws_size,
                              hipStream_t stream) {
    const float* x = (const float*)d_in[0];
    const int* ei = (const int*)d_in[1];
    const int* batch = (const int*)d_in[2];
    const float* W1 = (const float*)d_in[3];
    const float* aw_s1 = (const float*)d_in[4];
    const float* aw_d1 = (const float*)d_in[5];
    const float* b1 = (const float*)d_in[6];
    const float* W2 = (const float*)d_in[7];
    const float* aw_s2 = (const float*)d_in[8];
    const float* aw_d2 = (const float*)d_in[9];
    const float* b2 = (const float*)d_in[10];
    const float* Wl = (const float*)d_in[11];
    const float* bl = (const float*)d_in[12];
    const int* srcArr = ei;
    const int* dstArr = ei + EE;

    char* w = (char*)d_ws;
    size_t off = 0;
    auto alloc = [&](size_t bytes) -> void* {
        void* p = (void*)(w + off);
        off = (off + bytes + 255) & ~(size_t)255;
        return p;
    };
    // ~58 MB (alpha buffer removed vs R14's proven 71 MB)
    bf16* bufA = (bf16*)alloc((size_t)NN * 256 * 2);   // h1; later h2
    bf16* bufB = (bf16*)alloc((size_t)NN * 256 * 2);   // x2
    float* as1 = (float*)alloc((size_t)NN * 4 * 4);
    float* ad1 = (float*)alloc((size_t)NN * 4 * 4);
    float* as2 = (float*)alloc((size_t)NN * 4);
    float* ad2 = (float*)alloc((size_t)NN * 4);
    int* deg = (int*)alloc((size_t)NN * 4);
    int* offs = (int*)alloc((size_t)(NN + 1) * 4);
    int* cur = (int*)alloc((size_t)NN * 4);   // after k_scatter: wt1+wt2
    int* csrc = (int*)alloc((size_t)ETOT * 4);
    int* bsum = (int*)alloc((size_t)NBLK * 4);
    int* boff = (int*)alloc((size_t)NBLK * 4);
    float* pooled = (float*)alloc((size_t)BB * 128 * 4);
    int* cnt = (int*)alloc((size_t)BB * 4);
    (void)ws_size;

    bf16* wt1 = (bf16*)cur;
    bf16* wt2 = (bf16*)cur + 256 * 128;

    k_init<<<256, 256, 0, stream>>>(deg, pooled, cnt);

    k_count<<<(ETOT + 255) / 256, 256, 0, stream>>>(dstArr, deg);
    k_scan1<<<NBLK, 256, 0, stream>>>(deg, offs, cur, bsum);
    k_scan2<<<1, 256, 0, stream>>>(bsum, boff, offs);
    k_scan3<<<NBLK, 256, 0, stream>>>(boff, offs, cur, batch, cnt);
    k_scatter<<<(ETOT + 255) / 256, 256, 0, stream>>>(srcArr, dstArr, cur, csrc);

    // cur dead -> transposed bf16 weights
    k_cvtw<<<256, 256, 0, stream>>>(W1, W2, wt1, wt2);

    bf16* h1 = bufA;
    bf16* x2 = bufB;
    k_gemm1<<<(NN + 31) / 32, 256, 0, stream>>>(x, wt1, aw_s1, aw_d1, h1, as1, ad1);
    k_gather1<<<NN, 64, 0, stream>>>(csrc, offs, h1, as1, ad1, b1, x2);

    bf16* h2 = bufA;  // h1 dead after gather1
    k_gemm2<<<(NN + 63) / 64, 256, 0, stream>>>(x2, wt2, aw_s2, aw_d2, h2, as2, ad2);

    k_gather2<<<NN, 64, 0, stream>>>(csrc, offs, h2, as2, ad2, b2, batch, pooled);

    k_final<<<2, 256, 0, stream>>>(pooled, cnt, Wl, bl, (float*)d_out);
}